// Round 2
// baseline (6589.246 us; speedup 1.0000x reference)
//
#include <hip/hip_runtime.h>
#include <math.h>

#define EMBED   1024
#define HEADS   16
#define HEAD_DIM 64
#define NEXP    8
#define HIDDEN  2752
#define SEQ     2048
#define BATCH   2
#define NTOK    (BATCH*SEQ)   // 4096

// ---------------- workspace layout (float offsets) ----------------
#define OFF_ROPE_C 0
#define OFF_ROPE_S (OFF_ROPE_C + SEQ*32)
#define OFF_XN1    (OFF_ROPE_S + SEQ*32)
#define OFF_Q      (OFF_XN1 + (size_t)NTOK*EMBED)
#define OFF_K      (OFF_Q   + (size_t)NTOK*EMBED)
#define OFF_V      (OFF_K   + (size_t)NTOK*EMBED)
#define OFF_XN2    (OFF_V   + (size_t)NTOK*EMBED)
#define OFF_WSLOT  (OFF_XN2 + (size_t)NTOK*EMBED)
#define OFF_ACT    (OFF_WSLOT + (size_t)NTOK*2)
#define OFF_INTS   (OFF_ACT + (size_t)NTOK*2*HIDDEN)   // counts[8], lists[8*NTOK]
// attn output aliases XN1 (dead after QKV projections)

// ---------------- RoPE tables (double precision to match numpy) ----------------
__global__ void rope_table_kernel(float* __restrict__ cosT, float* __restrict__ sinT,
                                  int* __restrict__ counts) {
    int idx = blockIdx.x * blockDim.x + threadIdx.x;
    if (blockIdx.x == 0 && threadIdx.x < NEXP) counts[threadIdx.x] = 0;
    if (idx >= SEQ * 32) return;
    int s = idx >> 5, d = idx & 31;
    double inv = pow(10000.0, -(double)(2 * d) / 64.0);
    double ang = (double)s * inv;
    cosT[idx] = (float)cos(ang);
    sinT[idx] = (float)sin(ang);
}

// ---------------- RMSNorm: one block per token ----------------
__global__ __launch_bounds__(256) void rmsnorm_kernel(const float* __restrict__ x,
                                                      const float* __restrict__ g,
                                                      float* __restrict__ o) {
    int t = blockIdx.x;
    int tid = threadIdx.x;
    const float4* xr = (const float4*)(x + (size_t)t * EMBED);
    float4 v = xr[tid];
    float ss = v.x*v.x + v.y*v.y + v.z*v.z + v.w*v.w;
#pragma unroll
    for (int off = 1; off < 64; off <<= 1) ss += __shfl_xor(ss, off);
    __shared__ float red[4];
    if ((tid & 63) == 0) red[tid >> 6] = ss;
    __syncthreads();
    float tot = red[0] + red[1] + red[2] + red[3];
    float rr = 1.0f / sqrtf(tot * (1.0f / EMBED) + 1e-6f);
    float4 gv = ((const float4*)g)[tid];
    float4 ov;
    ov.x = v.x * rr * gv.x; ov.y = v.y * rr * gv.y;
    ov.z = v.z * rr * gv.z; ov.w = v.w * rr * gv.w;
    ((float4*)(o + (size_t)t * EMBED))[tid] = ov;
}

// ---------------- fused QKV: 128x128 tile, 8x8 microtile ----------------
__global__ __launch_bounds__(256) void qkv_gemm(const float* __restrict__ A,
                                                const float* __restrict__ wq,
                                                const float* __restrict__ wk,
                                                const float* __restrict__ wv,
                                                float* __restrict__ qo,
                                                float* __restrict__ ko,
                                                float* __restrict__ vo) {
    __shared__ float As[16][132];
    __shared__ float Bs[16][132];
    int bm = blockIdx.x * 128;
    int by = blockIdx.y;
    int sel = by >> 3;
    int bn = (by & 7) * 128;
    const float* W = (sel == 0) ? wq : (sel == 1) ? wk : wv;
    float* C = (sel == 0) ? qo : (sel == 1) ? ko : vo;
    const int K = EMBED, N = EMBED;
    int tid = threadIdx.x;
    int alr = tid >> 1, alc = (tid & 1) * 8;
    int br = tid >> 4, bc = (tid & 15) * 8;
    int ty = tid >> 4, tx = tid & 15;
    float acc[8][8] = {};
    const float* Arow = A + (size_t)(bm + alr) * K + alc;
    for (int k0 = 0; k0 < K; k0 += 16) {
        float4 a0 = *(const float4*)(Arow + k0);
        float4 a1 = *(const float4*)(Arow + k0 + 4);
        float4 b0 = *(const float4*)(W + (size_t)(k0 + br) * N + bn + bc);
        float4 b1 = *(const float4*)(W + (size_t)(k0 + br) * N + bn + bc + 4);
        As[alc+0][alr]=a0.x; As[alc+1][alr]=a0.y; As[alc+2][alr]=a0.z; As[alc+3][alr]=a0.w;
        As[alc+4][alr]=a1.x; As[alc+5][alr]=a1.y; As[alc+6][alr]=a1.z; As[alc+7][alr]=a1.w;
        *(float4*)&Bs[br][bc]     = b0;
        *(float4*)&Bs[br][bc + 4] = b1;
        __syncthreads();
#pragma unroll
        for (int kk = 0; kk < 16; kk++) {
            float av[8], bv[8];
            *(float4*)&av[0] = *(const float4*)&As[kk][ty * 8];
            *(float4*)&av[4] = *(const float4*)&As[kk][ty * 8 + 4];
            *(float4*)&bv[0] = *(const float4*)&Bs[kk][tx * 8];
            *(float4*)&bv[4] = *(const float4*)&Bs[kk][tx * 8 + 4];
#pragma unroll
            for (int i = 0; i < 8; i++)
#pragma unroll
                for (int j = 0; j < 8; j++)
                    acc[i][j] = fmaf(av[i], bv[j], acc[i][j]);
        }
        __syncthreads();
    }
#pragma unroll
    for (int i = 0; i < 8; i++) {
        size_t row = bm + ty * 8 + i;
        float4 o0 = { acc[i][0], acc[i][1], acc[i][2], acc[i][3] };
        float4 o1 = { acc[i][4], acc[i][5], acc[i][6], acc[i][7] };
        *(float4*)(C + row * N + bn + tx * 8)     = o0;
        *(float4*)(C + row * N + bn + tx * 8 + 4) = o1;
    }
}

// ---------------- generic 128x128 GEMM (+optional residual) ----------------
template<bool RESID>
__global__ __launch_bounds__(256) void gemm128(const float* __restrict__ A,
                                               const float* __restrict__ W,
                                               const float* __restrict__ R,
                                               float* __restrict__ C,
                                               int K, int N) {
    __shared__ float As[16][132];
    __shared__ float Bs[16][132];
    int bm = blockIdx.x * 128;
    int bn = blockIdx.y * 128;
    int tid = threadIdx.x;
    int alr = tid >> 1, alc = (tid & 1) * 8;
    int br = tid >> 4, bc = (tid & 15) * 8;
    int ty = tid >> 4, tx = tid & 15;
    float acc[8][8] = {};
    const float* Arow = A + (size_t)(bm + alr) * K + alc;
    for (int k0 = 0; k0 < K; k0 += 16) {
        float4 a0 = *(const float4*)(Arow + k0);
        float4 a1 = *(const float4*)(Arow + k0 + 4);
        float4 b0 = *(const float4*)(W + (size_t)(k0 + br) * N + bn + bc);
        float4 b1 = *(const float4*)(W + (size_t)(k0 + br) * N + bn + bc + 4);
        As[alc+0][alr]=a0.x; As[alc+1][alr]=a0.y; As[alc+2][alr]=a0.z; As[alc+3][alr]=a0.w;
        As[alc+4][alr]=a1.x; As[alc+5][alr]=a1.y; As[alc+6][alr]=a1.z; As[alc+7][alr]=a1.w;
        *(float4*)&Bs[br][bc]     = b0;
        *(float4*)&Bs[br][bc + 4] = b1;
        __syncthreads();
#pragma unroll
        for (int kk = 0; kk < 16; kk++) {
            float av[8], bv[8];
            *(float4*)&av[0] = *(const float4*)&As[kk][ty * 8];
            *(float4*)&av[4] = *(const float4*)&As[kk][ty * 8 + 4];
            *(float4*)&bv[0] = *(const float4*)&Bs[kk][tx * 8];
            *(float4*)&bv[4] = *(const float4*)&Bs[kk][tx * 8 + 4];
#pragma unroll
            for (int i = 0; i < 8; i++)
#pragma unroll
                for (int j = 0; j < 8; j++)
                    acc[i][j] = fmaf(av[i], bv[j], acc[i][j]);
        }
        __syncthreads();
    }
#pragma unroll
    for (int i = 0; i < 8; i++) {
        size_t row = bm + ty * 8 + i;
        float4 o0 = { acc[i][0], acc[i][1], acc[i][2], acc[i][3] };
        float4 o1 = { acc[i][4], acc[i][5], acc[i][6], acc[i][7] };
        if (RESID) {
            float4 r0 = *(const float4*)(R + row * N + bn + tx * 8);
            float4 r1 = *(const float4*)(R + row * N + bn + tx * 8 + 4);
            o0.x += r0.x; o0.y += r0.y; o0.z += r0.z; o0.w += r0.w;
            o1.x += r1.x; o1.y += r1.y; o1.z += r1.z; o1.w += r1.w;
        }
        *(float4*)(C + row * N + bn + tx * 8)     = o0;
        *(float4*)(C + row * N + bn + tx * 8 + 4) = o1;
    }
}

// ---------------- RoPE apply (q,k in [T, H*D] layout) ----------------
__global__ void rope_kernel(float* __restrict__ q, float* __restrict__ k,
                            const float* __restrict__ cosT, const float* __restrict__ sinT) {
    int idx = blockIdx.x * blockDim.x + threadIdx.x;
    if (idx >= NTOK * HEADS * 32) return;
    int d = idx & 31;
    int h = (idx >> 5) & 15;
    int t = idx >> 9;
    int s = t & (SEQ - 1);
    float c = cosT[s * 32 + d], sn = sinT[s * 32 + d];
    size_t base = (size_t)t * EMBED + h * 64;
    float q1 = q[base + d], q2 = q[base + d + 32];
    q[base + d]      = q1 * c - q2 * sn;
    q[base + d + 32] = q2 * c + q1 * sn;
    float k1 = k[base + d], k2 = k[base + d + 32];
    k[base + d]      = k1 * c - k2 * sn;
    k[base + d + 32] = k2 * c + k1 * sn;
}

// ---------------- flash attention: block = 32 queries x one (b,h) ----------------
__global__ __launch_bounds__(256) void attn_kernel(const float* __restrict__ q,
                                                   const float* __restrict__ k,
                                                   const float* __restrict__ v,
                                                   float* __restrict__ o) {
    __shared__ float Qs[32][68], Ks[32][68], Vs[32][68];
    __shared__ float Ss[32][36];
    int qt = blockIdx.x;
    int bh = blockIdx.y;
    int b = bh >> 4, h = bh & 15;
    int tid = threadIdx.x;
    int qi = tid >> 3, j = tid & 7;

    {   // load Q tile
        int c = j * 8;
        size_t gq = ((size_t)(b * SEQ + qt * 32 + qi)) * EMBED + h * 64 + c;
        *(float4*)&Qs[qi][c]     = *(const float4*)&q[gq];
        *(float4*)&Qs[qi][c + 4] = *(const float4*)&q[gq + 4];
    }
    float O[8] = {};
    float m = -INFINITY, l = 0.0f;
    const float scale = 0.125f;
    int qg = qt * 32 + qi;

    for (int kt = 0; kt <= qt; ++kt) {
        __syncthreads();   // protect Ks/Vs from previous iteration readers
        {
            int c = j * 8;
            size_t gk = ((size_t)(b * SEQ + kt * 32 + qi)) * EMBED + h * 64 + c;
            *(float4*)&Ks[qi][c]     = *(const float4*)&k[gk];
            *(float4*)&Ks[qi][c + 4] = *(const float4*)&k[gk + 4];
            *(float4*)&Vs[qi][c]     = *(const float4*)&v[gk];
            *(float4*)&Vs[qi][c + 4] = *(const float4*)&v[gk + 4];
        }
        __syncthreads();
        float sc[4];
#pragma unroll
        for (int kkk = 0; kkk < 4; kkk++) {
            int kk = j + 8 * kkk;
            float acc = 0.0f;
#pragma unroll
            for (int dd = 0; dd < 64; dd += 4) {
                float4 qv = *(const float4*)&Qs[qi][dd];
                float4 kv = *(const float4*)&Ks[kk][dd];
                acc = fmaf(qv.x, kv.x, acc); acc = fmaf(qv.y, kv.y, acc);
                acc = fmaf(qv.z, kv.z, acc); acc = fmaf(qv.w, kv.w, acc);
            }
            int kg = kt * 32 + kk;
            sc[kkk] = (kg <= qg) ? acc * scale : -INFINITY;
        }
        float tmax = fmaxf(fmaxf(sc[0], sc[1]), fmaxf(sc[2], sc[3]));
#pragma unroll
        for (int off = 1; off < 8; off <<= 1) tmax = fmaxf(tmax, __shfl_xor(tmax, off));
        float mnew = fmaxf(m, tmax);
        float p[4], ls = 0.0f;
#pragma unroll
        for (int kkk = 0; kkk < 4; kkk++) { p[kkk] = expf(sc[kkk] - mnew); ls += p[kkk]; }
#pragma unroll
        for (int off = 1; off < 8; off <<= 1) ls += __shfl_xor(ls, off);
        float sc_old = expf(m - mnew);
        l = l * sc_old + ls;
#pragma unroll
        for (int dd = 0; dd < 8; dd++) O[dd] *= sc_old;
        m = mnew;
#pragma unroll
        for (int kkk = 0; kkk < 4; kkk++) Ss[qi][j + 8 * kkk] = p[kkk];
        __syncthreads();
#pragma unroll
        for (int kk = 0; kk < 32; kk++) {
            float pv = Ss[qi][kk];
            float4 v0 = *(const float4*)&Vs[kk][j * 8];
            float4 v1 = *(const float4*)&Vs[kk][j * 8 + 4];
            O[0] = fmaf(pv, v0.x, O[0]); O[1] = fmaf(pv, v0.y, O[1]);
            O[2] = fmaf(pv, v0.z, O[2]); O[3] = fmaf(pv, v0.w, O[3]);
            O[4] = fmaf(pv, v1.x, O[4]); O[5] = fmaf(pv, v1.y, O[5]);
            O[6] = fmaf(pv, v1.z, O[6]); O[7] = fmaf(pv, v1.w, O[7]);
        }
    }
    float inv = 1.0f / l;
    size_t go = ((size_t)(b * SEQ + qt * 32 + qi)) * EMBED + h * 64 + j * 8;
    float4 o0 = { O[0] * inv, O[1] * inv, O[2] * inv, O[3] * inv };
    float4 o1 = { O[4] * inv, O[5] * inv, O[6] * inv, O[7] * inv };
    *(float4*)&o[go]     = o0;
    *(float4*)&o[go + 4] = o1;
}

// ---------------- router: one wave per token, top-2 dispatch ----------------
__global__ __launch_bounds__(64) void router_kernel(const float* __restrict__ xn2,
                                                    const float* __restrict__ wr,
                                                    float* __restrict__ wslot,
                                                    int* __restrict__ counts,
                                                    int* __restrict__ lists) {
    int t = blockIdx.x;
    int lane = threadIdx.x;
    float acc[NEXP] = {};
    for (int i = lane; i < EMBED; i += 64) {
        float xv = xn2[(size_t)t * EMBED + i];
        const float* wrow = wr + (size_t)i * NEXP;
#pragma unroll
        for (int e = 0; e < NEXP; e++) acc[e] = fmaf(xv, wrow[e], acc[e]);
    }
#pragma unroll
    for (int off = 1; off < 64; off <<= 1)
#pragma unroll
        for (int e = 0; e < NEXP; e++) acc[e] += __shfl_xor(acc[e], off);
    if (lane == 0) {
        int e1 = 0; float b1 = acc[0];
#pragma unroll
        for (int e = 1; e < NEXP; e++) if (acc[e] > b1) { b1 = acc[e]; e1 = e; }
        int e2 = -1; float b2 = -INFINITY;
#pragma unroll
        for (int e = 0; e < NEXP; e++) if (e != e1 && acc[e] > b2) { b2 = acc[e]; e2 = e; }
        float p2 = expf(b2 - b1);
        float inv = 1.0f / (1.0f + p2);
        int pos1 = atomicAdd(&counts[e1], 1);
        lists[e1 * NTOK + pos1] = (t << 1) | 0;
        wslot[t * 2 + 0] = inv;
        int pos2 = atomicAdd(&counts[e2], 1);
        lists[e2 * NTOK + pos2] = (t << 1) | 1;
        wslot[t * 2 + 1] = p2 * inv;
    }
}

// ---------------- MoE gate+up: 128x64 tile, 8x4 microtile (x2 outputs) ----------------
__global__ __launch_bounds__(256) void moe_gateup(const float* __restrict__ xn2,
                                                  const float* __restrict__ wg,
                                                  const float* __restrict__ wu,
                                                  const int* __restrict__ lists,
                                                  const int* __restrict__ counts,
                                                  float* __restrict__ act) {
    int e = blockIdx.z;
    int cnt = counts[e];
    int bm = blockIdx.x * 128;
    if (bm >= cnt) return;
    int bn = blockIdx.y * 64;
    __shared__ float As[16][132];
    __shared__ float Gs[16][68], Us[16][68];
    __shared__ int toks[128];
    int tid = threadIdx.x;
    if (tid < 128) {
        int i = bm + tid;
        toks[tid] = lists[e * NTOK + ((i < cnt) ? i : (cnt - 1))];
    }
    __syncthreads();
    int alr = tid >> 1, alc = (tid & 1) * 8;
    int br = tid >> 4, bc = (tid & 15) * 4;
    int ty = tid >> 4, tx = tid & 15;
    const float* Arow = xn2 + (size_t)(toks[alr] >> 1) * EMBED + alc;
    const float* wgb = wg + (size_t)e * EMBED * HIDDEN;
    const float* wub = wu + (size_t)e * EMBED * HIDDEN;
    float ag[8][4] = {}, au[8][4] = {};
    for (int k0 = 0; k0 < EMBED; k0 += 16) {
        float4 a0 = *(const float4*)(Arow + k0);
        float4 a1 = *(const float4*)(Arow + k0 + 4);
        float4 g4 = *(const float4*)(wgb + (size_t)(k0 + br) * HIDDEN + bn + bc);
        float4 u4 = *(const float4*)(wub + (size_t)(k0 + br) * HIDDEN + bn + bc);
        As[alc+0][alr]=a0.x; As[alc+1][alr]=a0.y; As[alc+2][alr]=a0.z; As[alc+3][alr]=a0.w;
        As[alc+4][alr]=a1.x; As[alc+5][alr]=a1.y; As[alc+6][alr]=a1.z; As[alc+7][alr]=a1.w;
        *(float4*)&Gs[br][bc] = g4;
        *(float4*)&Us[br][bc] = u4;
        __syncthreads();
#pragma unroll
        for (int kk = 0; kk < 16; kk++) {
            float av[8], gv[4], uv[4];
            *(float4*)&av[0] = *(const float4*)&As[kk][ty * 8];
            *(float4*)&av[4] = *(const float4*)&As[kk][ty * 8 + 4];
            *(float4*)&gv[0] = *(const float4*)&Gs[kk][tx * 4];
            *(float4*)&uv[0] = *(const float4*)&Us[kk][tx * 4];
#pragma unroll
            for (int i = 0; i < 8; i++)
#pragma unroll
                for (int j = 0; j < 4; j++) {
                    ag[i][j] = fmaf(av[i], gv[j], ag[i][j]);
                    au[i][j] = fmaf(av[i], uv[j], au[i][j]);
                }
        }
        __syncthreads();
    }
#pragma unroll
    for (int i = 0; i < 8; i++) {
        int lr = ty * 8 + i;
        if (bm + lr >= cnt) continue;
        int entry = toks[lr];
        float4 r;
        r.x = (ag[i][0] / (1.0f + expf(-ag[i][0]))) * au[i][0];
        r.y = (ag[i][1] / (1.0f + expf(-ag[i][1]))) * au[i][1];
        r.z = (ag[i][2] / (1.0f + expf(-ag[i][2]))) * au[i][2];
        r.w = (ag[i][3] / (1.0f + expf(-ag[i][3]))) * au[i][3];
        *(float4*)(act + (size_t)entry * HIDDEN + bn + tx * 4) = r;
    }
}

// ---------------- MoE down: 128x128 tile, 8x8 microtile, weighted scatter-add ----------------
__global__ __launch_bounds__(256) void moe_down(const float* __restrict__ act,
                                                const float* __restrict__ wd,
                                                const int* __restrict__ lists,
                                                const int* __restrict__ counts,
                                                const float* __restrict__ wslot,
                                                float* __restrict__ out) {
    int e = blockIdx.z;
    int cnt = counts[e];
    int bm = blockIdx.x * 128;
    if (bm >= cnt) return;
    int bn = blockIdx.y * 128;
    __shared__ float As[16][132];
    __shared__ float Bs[16][132];
    __shared__ int toks[128];
    int tid = threadIdx.x;
    if (tid < 128) {
        int i = bm + tid;
        toks[tid] = lists[e * NTOK + ((i < cnt) ? i : (cnt - 1))];
    }
    __syncthreads();
    int alr = tid >> 1, alc = (tid & 1) * 8;
    int br = tid >> 4, bc = (tid & 15) * 8;
    int ty = tid >> 4, tx = tid & 15;
    const float* Arow = act + (size_t)toks[alr] * HIDDEN + alc;
    const float* wdb = wd + (size_t)e * HIDDEN * EMBED;
    float acc[8][8] = {};
    for (int k0 = 0; k0 < HIDDEN; k0 += 16) {
        float4 a0 = *(const float4*)(Arow + k0);
        float4 a1 = *(const float4*)(Arow + k0 + 4);
        float4 b0 = *(const float4*)(wdb + (size_t)(k0 + br) * EMBED + bn + bc);
        float4 b1 = *(const float4*)(wdb + (size_t)(k0 + br) * EMBED + bn + bc + 4);
        As[alc+0][alr]=a0.x; As[alc+1][alr]=a0.y; As[alc+2][alr]=a0.z; As[alc+3][alr]=a0.w;
        As[alc+4][alr]=a1.x; As[alc+5][alr]=a1.y; As[alc+6][alr]=a1.z; As[alc+7][alr]=a1.w;
        *(float4*)&Bs[br][bc]     = b0;
        *(float4*)&Bs[br][bc + 4] = b1;
        __syncthreads();
#pragma unroll
        for (int kk = 0; kk < 16; kk++) {
            float av[8], bv[8];
            *(float4*)&av[0] = *(const float4*)&As[kk][ty * 8];
            *(float4*)&av[4] = *(const float4*)&As[kk][ty * 8 + 4];
            *(float4*)&bv[0] = *(const float4*)&Bs[kk][tx * 8];
            *(float4*)&bv[4] = *(const float4*)&Bs[kk][tx * 8 + 4];
#pragma unroll
            for (int i = 0; i < 8; i++)
#pragma unroll
                for (int j = 0; j < 8; j++)
                    acc[i][j] = fmaf(av[i], bv[j], acc[i][j]);
        }
        __syncthreads();
    }
#pragma unroll
    for (int i = 0; i < 8; i++) {
        int lr = ty * 8 + i;
        if (bm + lr >= cnt) continue;
        int entry = toks[lr];
        float w = wslot[entry];
        float* op = out + (size_t)(entry >> 1) * EMBED + bn + tx * 8;
#pragma unroll
        for (int j = 0; j < 8; j++)
            atomicAdd(op + j, w * acc[i][j]);
    }
}

// ---------------- launch ----------------
extern "C" void kernel_launch(void* const* d_in, const int* in_sizes, int n_in,
                              void* d_out, int out_size, void* d_ws, size_t ws_size,
                              hipStream_t stream) {
    const float* x  = (const float*)d_in[0];
    const float* wq = (const float*)d_in[1];
    const float* wk = (const float*)d_in[2];
    const float* wv = (const float*)d_in[3];
    const float* wo = (const float*)d_in[4];
    const float* wr = (const float*)d_in[5];
    const float* wg = (const float*)d_in[6];
    const float* wu = (const float*)d_in[7];
    const float* wd = (const float*)d_in[8];
    const float* g1 = (const float*)d_in[9];
    const float* g2 = (const float*)d_in[10];
    float* out = (float*)d_out;

    float* ws     = (float*)d_ws;
    float* ropeC  = ws + OFF_ROPE_C;
    float* ropeS  = ws + OFF_ROPE_S;
    float* xn1    = ws + OFF_XN1;
    float* qb     = ws + OFF_Q;
    float* kb     = ws + OFF_K;
    float* vb     = ws + OFF_V;
    float* attnb  = xn1;                 // alias: xn1 dead after QKV
    float* xn2    = ws + OFF_XN2;
    float* wslot  = ws + OFF_WSLOT;
    float* act    = ws + OFF_ACT;
    int*   counts = (int*)(ws + OFF_INTS);
    int*   lists  = counts + NEXP;

    // 1. rope tables (+ zero expert counters)
    rope_table_kernel<<<(SEQ * 32 + 255) / 256, 256, 0, stream>>>(ropeC, ropeS, counts);
    // 2. rmsnorm(x, g1) -> xn1
    rmsnorm_kernel<<<NTOK, 256, 0, stream>>>(x, g1, xn1);
    // 3. fused QKV projections (grid.y: 0-7 wq, 8-15 wk, 16-23 wv)
    qkv_gemm<<<dim3(NTOK / 128, 24), 256, 0, stream>>>(xn1, wq, wk, wv, qb, kb, vb);
    // 4. rope on q,k
    rope_kernel<<<(NTOK * HEADS * 32 + 255) / 256, 256, 0, stream>>>(qb, kb, ropeC, ropeS);
    // 5. flash attention -> attnb (aliases xn1)
    attn_kernel<<<dim3(SEQ / 32, BATCH * HEADS), 256, 0, stream>>>(qb, kb, vb, attnb);
    // 6. out proj + residual: d_out = attnb @ wo + x   (this is h)
    gemm128<true><<<dim3(NTOK / 128, EMBED / 128), 256, 0, stream>>>(attnb, wo, x, out, EMBED, EMBED);
    // 7. rmsnorm(h, g2) -> xn2
    rmsnorm_kernel<<<NTOK, 256, 0, stream>>>(out, g2, xn2);
    // 8. router + top-2 dispatch
    router_kernel<<<NTOK, 64, 0, stream>>>(xn2, wr, wslot, counts, lists);
    // 9. expert gate+up -> act
    moe_gateup<<<dim3(NTOK / 128, HIDDEN / 64, NEXP), 256, 0, stream>>>(xn2, wg, wu, lists, counts, act);
    // 10. expert down + weighted scatter-add into d_out (d_out already holds h)
    moe_down<<<dim3(NTOK / 128, EMBED / 128, NEXP), 256, 0, stream>>>(act, wd, lists, counts, wslot, out);
}

// Round 3
// 2583.959 us; speedup vs baseline: 2.5501x; 2.5501x over previous
//
#include <hip/hip_runtime.h>
#include <math.h>

#define EMBED   1024
#define HEADS   16
#define NEXP    8
#define HIDDEN  2752
#define HPAD    2816          // HIDDEN padded to 128 multiple (zero-filled)
#define SEQ     2048
#define BATCH   2
#define NTOK    (BATCH*SEQ)   // 4096

typedef _Float16 f16;
typedef __attribute__((ext_vector_type(8))) _Float16 f16x8;
typedef __attribute__((ext_vector_type(4))) float    f32x4;

// ---------------- workspace layout (float-unit offsets, all 16B aligned) ----------------
#define OFF_ROPE_C 0
#define OFF_ROPE_S (OFF_ROPE_C + 65536)
#define OFF_Q      (OFF_ROPE_S + 65536)           // q,k,v region; later aliased by act (f16, 11.54M fl needed <= 12.58M)
#define OFF_K      (OFF_Q   + 4194304)
#define OFF_V      (OFF_K   + 4194304)
#define OFF_XN2    (OFF_V   + 4194304)
#define OFF_WSLOT  (OFF_XN2 + 4194304)
#define OFF_INTS   (OFF_WSLOT + 8192)             // counts[8] + lists[8*4096]
#define OFF_XN1H   (OFF_INTS + 40000)             // f16 4096x1024 (2.1M floats); aliased by attnbh after QKV
#define OFF_XN2H   (OFF_XN1H + 2097152)
#define OFF_WQH    (OFF_XN2H + 2097152)
#define OFF_WKH    (OFF_WQH + 524288)
#define OFF_WVH    (OFF_WKH + 524288)
#define OFF_WOH    (OFF_WVH + 524288)
#define OFF_WGH    (OFF_WOH + 524288)             // [8][2816][1024] f16 = 11.53M floats
#define OFF_WUH    (OFF_WGH + 11534336)
#define OFF_WDH    (OFF_WUH + 11534336)           // [8][1024][2816] f16

// async global->LDS, 16B per lane (LDS dest = wave-uniform base + lane*16)
__device__ __forceinline__ void gll16(void* lds, const void* g) {
    __builtin_amdgcn_global_load_lds(
        (const __attribute__((address_space(1))) unsigned int*)g,
        (__attribute__((address_space(3))) unsigned int*)lds, 16, 0, 0);
}

// ---------------- RoPE tables (double precision) + zero counters ----------------
__global__ void rope_table_kernel(float* __restrict__ cosT, float* __restrict__ sinT,
                                  int* __restrict__ counts) {
    int idx = blockIdx.x * blockDim.x + threadIdx.x;
    if (blockIdx.x == 0 && threadIdx.x < NEXP) counts[threadIdx.x] = 0;
    if (idx >= SEQ * 32) return;
    int s = idx >> 5, d = idx & 31;
    double inv = pow(10000.0, -(double)(2 * d) / 64.0);
    double ang = (double)s * inv;
    cosT[idx] = (float)cos(ang);
    sinT[idx] = (float)sin(ang);
}

// ---------------- transpose + fp32->fp16: src[K][N] -> dst[NP][KP], zero-padded ----------------
__global__ __launch_bounds__(256) void transpose_f32_f16(const float* __restrict__ src,
                                                         f16* __restrict__ dst,
                                                         int K, int N, int KP, int NP,
                                                         long sstride, long dstride) {
    src += (size_t)blockIdx.z * sstride;
    dst += (size_t)blockIdx.z * dstride;
    __shared__ float t[64][65];
    int kb = blockIdx.x * 64, nb = blockIdx.y * 64;
    int tid = threadIdx.x;
    int nc = (tid & 15) * 4, kr = tid >> 4;
#pragma unroll
    for (int r = 0; r < 4; r++) {
        int k = kb + kr + r * 16;
        float4 v = {0.f, 0.f, 0.f, 0.f};
        if (k < K && nb + nc < N)   // N is a multiple of 64 -> whole float4 in range
            v = *(const float4*)&src[(size_t)k * N + nb + nc];
        t[nc + 0][kr + r * 16] = v.x;
        t[nc + 1][kr + r * 16] = v.y;
        t[nc + 2][kr + r * 16] = v.z;
        t[nc + 3][kr + r * 16] = v.w;
    }
    __syncthreads();
    int kc = (tid & 7) * 8, nr = tid >> 3;
#pragma unroll
    for (int r = 0; r < 2; r++) {
        int n = nr + r * 32;
        f16x8 o;
#pragma unroll
        for (int i = 0; i < 8; i++) o[i] = (f16)t[n][kc + i];
        *(f16x8*)&dst[(size_t)(nb + n) * KP + kb + kc] = o;
    }
}

// ---------------- RMSNorm: one block per token; writes f16 (and optional f32) ----------------
template<int DUAL>
__global__ __launch_bounds__(256) void rmsnorm_kernel(const float* __restrict__ x,
                                                      const float* __restrict__ g,
                                                      float* __restrict__ o32,
                                                      f16* __restrict__ o16) {
    int t = blockIdx.x;
    int tid = threadIdx.x;
    const float4* xr = (const float4*)(x + (size_t)t * EMBED);
    float4 v = xr[tid];
    float ss = v.x*v.x + v.y*v.y + v.z*v.z + v.w*v.w;
#pragma unroll
    for (int off = 1; off < 64; off <<= 1) ss += __shfl_xor(ss, off);
    __shared__ float red[4];
    if ((tid & 63) == 0) red[tid >> 6] = ss;
    __syncthreads();
    float tot = red[0] + red[1] + red[2] + red[3];
    float rr = 1.0f / sqrtf(tot * (1.0f / EMBED) + 1e-6f);
    float4 gv = ((const float4*)g)[tid];
    float4 ov;
    ov.x = v.x * rr * gv.x; ov.y = v.y * rr * gv.y;
    ov.z = v.z * rr * gv.z; ov.w = v.w * rr * gv.w;
    if (DUAL) ((float4*)(o32 + (size_t)t * EMBED))[tid] = ov;
    typedef __attribute__((ext_vector_type(4))) _Float16 f16x4;
    f16x4 oh; oh[0] = (f16)ov.x; oh[1] = (f16)ov.y; oh[2] = (f16)ov.z; oh[3] = (f16)ov.w;
    *(f16x4*)(o16 + (size_t)t * EMBED + tid * 4) = oh;
}

// ---------------- fused QKV MFMA GEMM: [4096,1024]x[1024,1024] x3 ----------------
__global__ __launch_bounds__(256) void gemm_qkv(const f16* __restrict__ xh,
                                                const f16* __restrict__ wqh,
                                                const f16* __restrict__ wkh,
                                                const f16* __restrict__ wvh,
                                                float* __restrict__ q,
                                                float* __restrict__ k,
                                                float* __restrict__ v) {
    int sel = blockIdx.z;
    const f16* B = (sel == 0) ? wqh : (sel == 1) ? wkh : wvh;
    float* C = (sel == 0) ? q : (sel == 1) ? k : v;
    __shared__ f16 As[4096], Bs[4096];
    int tid = threadIdx.x, lane = tid & 63, w = tid >> 6;
    int wr = w >> 1, wc = w & 1;
    int bm = blockIdx.x * 128, bn = blockIdx.y * 128;
    const f16* ap[2]; const f16* bp[2];
#pragma unroll
    for (int i = 0; i < 2; i++) {
        int ms = w * 2 + i;
        ap[i] = xh + (size_t)(bm + ms * 16 + (lane & 15)) * 1024 + (lane >> 4) * 8;
        bp[i] = B  + (size_t)(bn + ms * 16 + (lane & 15)) * 1024 + (lane >> 4) * 8;
    }
    f32x4 acc[4][4] = {};
    for (int k0 = 0; k0 < 1024; k0 += 32) {
        __syncthreads();
#pragma unroll
        for (int i = 0; i < 2; i++) {
            gll16(&As[(w * 2 + i) * 512], ap[i] + k0);
            gll16(&Bs[(w * 2 + i) * 512], bp[i] + k0);
        }
        __syncthreads();
        f16x8 af[4];
#pragma unroll
        for (int m = 0; m < 4; m++) af[m] = *(const f16x8*)&As[((wr * 4 + m) * 64 + lane) * 8];
#pragma unroll
        for (int n = 0; n < 4; n++) {
            f16x8 bf = *(const f16x8*)&Bs[((wc * 4 + n) * 64 + lane) * 8];
#pragma unroll
            for (int m = 0; m < 4; m++)
                acc[m][n] = __builtin_amdgcn_mfma_f32_16x16x32_f16(af[m], bf, acc[m][n], 0, 0, 0);
        }
    }
#pragma unroll
    for (int m = 0; m < 4; m++)
#pragma unroll
        for (int r = 0; r < 4; r++) {
            int row = bm + (wr * 4 + m) * 16 + (lane >> 4) * 4 + r;
            float* crow = C + (size_t)row * 1024 + bn + (lane & 15);
#pragma unroll
            for (int n = 0; n < 4; n++) crow[(wc * 4 + n) * 16] = acc[m][n][r];
        }
}

// ---------------- WO MFMA GEMM + residual: out = attn@wo + x ----------------
__global__ __launch_bounds__(256) void gemm_wo(const f16* __restrict__ ah,
                                               const f16* __restrict__ wh,
                                               const float* __restrict__ R,
                                               float* __restrict__ C) {
    __shared__ f16 As[4096], Bs[4096];
    int tid = threadIdx.x, lane = tid & 63, w = tid >> 6;
    int wr = w >> 1, wc = w & 1;
    int bm = blockIdx.x * 128, bn = blockIdx.y * 128;
    const f16* ap[2]; const f16* bp[2];
#pragma unroll
    for (int i = 0; i < 2; i++) {
        int ms = w * 2 + i;
        ap[i] = ah + (size_t)(bm + ms * 16 + (lane & 15)) * 1024 + (lane >> 4) * 8;
        bp[i] = wh + (size_t)(bn + ms * 16 + (lane & 15)) * 1024 + (lane >> 4) * 8;
    }
    f32x4 acc[4][4] = {};
    for (int k0 = 0; k0 < 1024; k0 += 32) {
        __syncthreads();
#pragma unroll
        for (int i = 0; i < 2; i++) {
            gll16(&As[(w * 2 + i) * 512], ap[i] + k0);
            gll16(&Bs[(w * 2 + i) * 512], bp[i] + k0);
        }
        __syncthreads();
        f16x8 af[4];
#pragma unroll
        for (int m = 0; m < 4; m++) af[m] = *(const f16x8*)&As[((wr * 4 + m) * 64 + lane) * 8];
#pragma unroll
        for (int n = 0; n < 4; n++) {
            f16x8 bf = *(const f16x8*)&Bs[((wc * 4 + n) * 64 + lane) * 8];
#pragma unroll
            for (int m = 0; m < 4; m++)
                acc[m][n] = __builtin_amdgcn_mfma_f32_16x16x32_f16(af[m], bf, acc[m][n], 0, 0, 0);
        }
    }
#pragma unroll
    for (int m = 0; m < 4; m++)
#pragma unroll
        for (int r = 0; r < 4; r++) {
            int row = bm + (wr * 4 + m) * 16 + (lane >> 4) * 4 + r;
            const float* rrow = R + (size_t)row * 1024 + bn + (lane & 15);
            float* crow = C + (size_t)row * 1024 + bn + (lane & 15);
#pragma unroll
            for (int n = 0; n < 4; n++) crow[(wc * 4 + n) * 16] = acc[m][n][r] + rrow[(wc * 4 + n) * 16];
        }
}

// ---------------- RoPE apply (q,k fp32 in [T, H*D] layout) ----------------
__global__ void rope_kernel(float* __restrict__ q, float* __restrict__ k,
                            const float* __restrict__ cosT, const float* __restrict__ sinT) {
    int idx = blockIdx.x * blockDim.x + threadIdx.x;
    if (idx >= NTOK * HEADS * 32) return;
    int d = idx & 31;
    int h = (idx >> 5) & 15;
    int t = idx >> 9;
    int s = t & (SEQ - 1);
    float c = cosT[s * 32 + d], sn = sinT[s * 32 + d];
    size_t base = (size_t)t * EMBED + h * 64;
    float q1 = q[base + d], q2 = q[base + d + 32];
    q[base + d]      = q1 * c - q2 * sn;
    q[base + d + 32] = q2 * c + q1 * sn;
    float k1 = k[base + d], k2 = k[base + d + 32];
    k[base + d]      = k1 * c - k2 * sn;
    k[base + d + 32] = k2 * c + k1 * sn;
}

// ---------------- flash attention (fp32), writes f16 output ----------------
__global__ __launch_bounds__(256) void attn_kernel(const float* __restrict__ q,
                                                   const float* __restrict__ k,
                                                   const float* __restrict__ v,
                                                   f16* __restrict__ oh) {
    __shared__ float Qs[32][68], Ks[32][68], Vs[32][68];
    __shared__ float Ss[32][36];
    int qt = blockIdx.x;
    int bh = blockIdx.y;
    int b = bh >> 4, h = bh & 15;
    int tid = threadIdx.x;
    int qi = tid >> 3, j = tid & 7;
    {
        int c = j * 8;
        size_t gq = ((size_t)(b * SEQ + qt * 32 + qi)) * EMBED + h * 64 + c;
        *(float4*)&Qs[qi][c]     = *(const float4*)&q[gq];
        *(float4*)&Qs[qi][c + 4] = *(const float4*)&q[gq + 4];
    }
    float O[8] = {};
    float m = -INFINITY, l = 0.0f;
    const float scale = 0.125f;
    int qg = qt * 32 + qi;
    for (int kt = 0; kt <= qt; ++kt) {
        __syncthreads();
        {
            int c = j * 8;
            size_t gk = ((size_t)(b * SEQ + kt * 32 + qi)) * EMBED + h * 64 + c;
            *(float4*)&Ks[qi][c]     = *(const float4*)&k[gk];
            *(float4*)&Ks[qi][c + 4] = *(const float4*)&k[gk + 4];
            *(float4*)&Vs[qi][c]     = *(const float4*)&v[gk];
            *(float4*)&Vs[qi][c + 4] = *(const float4*)&v[gk + 4];
        }
        __syncthreads();
        float sc[4];
#pragma unroll
        for (int kkk = 0; kkk < 4; kkk++) {
            int kk = j + 8 * kkk;
            float acc = 0.0f;
#pragma unroll
            for (int dd = 0; dd < 64; dd += 4) {
                float4 qv = *(const float4*)&Qs[qi][dd];
                float4 kv = *(const float4*)&Ks[kk][dd];
                acc = fmaf(qv.x, kv.x, acc); acc = fmaf(qv.y, kv.y, acc);
                acc = fmaf(qv.z, kv.z, acc); acc = fmaf(qv.w, kv.w, acc);
            }
            int kg = kt * 32 + kk;
            sc[kkk] = (kg <= qg) ? acc * scale : -INFINITY;
        }
        float tmax = fmaxf(fmaxf(sc[0], sc[1]), fmaxf(sc[2], sc[3]));
#pragma unroll
        for (int off = 1; off < 8; off <<= 1) tmax = fmaxf(tmax, __shfl_xor(tmax, off));
        float mnew = fmaxf(m, tmax);
        float p[4], ls = 0.0f;
#pragma unroll
        for (int kkk = 0; kkk < 4; kkk++) { p[kkk] = expf(sc[kkk] - mnew); ls += p[kkk]; }
#pragma unroll
        for (int off = 1; off < 8; off <<= 1) ls += __shfl_xor(ls, off);
        float sc_old = expf(m - mnew);
        l = l * sc_old + ls;
#pragma unroll
        for (int dd = 0; dd < 8; dd++) O[dd] *= sc_old;
        m = mnew;
#pragma unroll
        for (int kkk = 0; kkk < 4; kkk++) Ss[qi][j + 8 * kkk] = p[kkk];
        __syncthreads();
#pragma unroll
        for (int kk = 0; kk < 32; kk++) {
            float pv = Ss[qi][kk];
            float4 v0 = *(const float4*)&Vs[kk][j * 8];
            float4 v1 = *(const float4*)&Vs[kk][j * 8 + 4];
            O[0] = fmaf(pv, v0.x, O[0]); O[1] = fmaf(pv, v0.y, O[1]);
            O[2] = fmaf(pv, v0.z, O[2]); O[3] = fmaf(pv, v0.w, O[3]);
            O[4] = fmaf(pv, v1.x, O[4]); O[5] = fmaf(pv, v1.y, O[5]);
            O[6] = fmaf(pv, v1.z, O[6]); O[7] = fmaf(pv, v1.w, O[7]);
        }
    }
    float inv = 1.0f / l;
    size_t go = ((size_t)(b * SEQ + qt * 32 + qi)) * EMBED + h * 64 + j * 8;
    f16x8 ov;
#pragma unroll
    for (int dd = 0; dd < 8; dd++) ov[dd] = (f16)(O[dd] * inv);
    *(f16x8*)&oh[go] = ov;
}

// ---------------- router: one wave per token, top-2 dispatch (fp32) ----------------
__global__ __launch_bounds__(64) void router_kernel(const float* __restrict__ xn2,
                                                    const float* __restrict__ wr,
                                                    float* __restrict__ wslot,
                                                    int* __restrict__ counts,
                                                    int* __restrict__ lists) {
    int t = blockIdx.x;
    int lane = threadIdx.x;
    float acc[NEXP] = {};
    for (int i = lane; i < EMBED; i += 64) {
        float xv = xn2[(size_t)t * EMBED + i];
        const float* wrow = wr + (size_t)i * NEXP;
#pragma unroll
        for (int e = 0; e < NEXP; e++) acc[e] = fmaf(xv, wrow[e], acc[e]);
    }
#pragma unroll
    for (int off = 1; off < 64; off <<= 1)
#pragma unroll
        for (int e = 0; e < NEXP; e++) acc[e] += __shfl_xor(acc[e], off);
    if (lane == 0) {
        int e1 = 0; float b1 = acc[0];
#pragma unroll
        for (int e = 1; e < NEXP; e++) if (acc[e] > b1) { b1 = acc[e]; e1 = e; }
        int e2 = -1; float b2 = -INFINITY;
#pragma unroll
        for (int e = 0; e < NEXP; e++) if (e != e1 && acc[e] > b2) { b2 = acc[e]; e2 = e; }
        float p2 = expf(b2 - b1);
        float inv = 1.0f / (1.0f + p2);
        int pos1 = atomicAdd(&counts[e1], 1);
        lists[e1 * NTOK + pos1] = (t << 1) | 0;
        wslot[t * 2 + 0] = inv;
        int pos2 = atomicAdd(&counts[e2], 1);
        lists[e2 * NTOK + pos2] = (t << 1) | 1;
        wslot[t * 2 + 1] = p2 * inv;
    }
}

// ---------------- MoE gate+up fused MFMA: act[entry] = silu(x@wg)*(x@wu), f16 ----------------
__global__ __launch_bounds__(256) void moe_gateup_mfma(const f16* __restrict__ xh2,
                                                       const f16* __restrict__ wgh,
                                                       const f16* __restrict__ wuh,
                                                       const int* __restrict__ lists,
                                                       const int* __restrict__ counts,
                                                       f16* __restrict__ act) {
    int e = blockIdx.z;
    int cnt = counts[e];
    int bm = blockIdx.x * 128;
    if (bm >= cnt) return;
    int bn = blockIdx.y * 128;
    __shared__ f16 As[4096], Gs[4096], Us[4096];
    __shared__ int toks[128];
    int tid = threadIdx.x, lane = tid & 63, w = tid >> 6;
    int wr = w >> 1, wc = w & 1;
    if (tid < 128) {
        int i = bm + tid;
        toks[tid] = lists[e * NTOK + ((i < cnt) ? i : (cnt - 1))];
    }
    __syncthreads();
    const f16* wgb = wgh + (size_t)e * HPAD * 1024;
    const f16* wub = wuh + (size_t)e * HPAD * 1024;
    const f16* ap[2]; const f16* gp[2]; const f16* up[2];
#pragma unroll
    for (int i = 0; i < 2; i++) {
        int ms = w * 2 + i;
        int entry = toks[ms * 16 + (lane & 15)];
        ap[i] = xh2 + (size_t)(entry >> 1) * 1024 + (lane >> 4) * 8;
        int col = bn + ms * 16 + (lane & 15);
        gp[i] = wgb + (size_t)col * 1024 + (lane >> 4) * 8;
        up[i] = wub + (size_t)col * 1024 + (lane >> 4) * 8;
    }
    f32x4 aG[4][4] = {}, aU[4][4] = {};
    for (int k0 = 0; k0 < 1024; k0 += 32) {
        __syncthreads();
#pragma unroll
        for (int i = 0; i < 2; i++) {
            gll16(&As[(w * 2 + i) * 512], ap[i] + k0);
            gll16(&Gs[(w * 2 + i) * 512], gp[i] + k0);
            gll16(&Us[(w * 2 + i) * 512], up[i] + k0);
        }
        __syncthreads();
        f16x8 af[4];
#pragma unroll
        for (int m = 0; m < 4; m++) af[m] = *(const f16x8*)&As[((wr * 4 + m) * 64 + lane) * 8];
#pragma unroll
        for (int n = 0; n < 4; n++) {
            f16x8 bg = *(const f16x8*)&Gs[((wc * 4 + n) * 64 + lane) * 8];
            f16x8 bu = *(const f16x8*)&Us[((wc * 4 + n) * 64 + lane) * 8];
#pragma unroll
            for (int m = 0; m < 4; m++) {
                aG[m][n] = __builtin_amdgcn_mfma_f32_16x16x32_f16(af[m], bg, aG[m][n], 0, 0, 0);
                aU[m][n] = __builtin_amdgcn_mfma_f32_16x16x32_f16(af[m], bu, aU[m][n], 0, 0, 0);
            }
        }
    }
#pragma unroll
    for (int m = 0; m < 4; m++)
#pragma unroll
        for (int r = 0; r < 4; r++) {
            int rl = (wr * 4 + m) * 16 + (lane >> 4) * 4 + r;
            if (bm + rl < cnt) {
                int entry = toks[rl];
                f16* arow = act + (size_t)entry * HPAD + bn + (lane & 15);
#pragma unroll
                for (int n = 0; n < 4; n++) {
                    float g = aG[m][n][r], u = aU[m][n][r];
                    arow[(wc * 4 + n) * 16] = (f16)(g / (1.0f + expf(-g)) * u);
                }
            }
        }
}

// ---------------- MoE down MFMA: out[t] += wslot * act[entry] @ wd ----------------
__global__ __launch_bounds__(256) void moe_down_mfma(const f16* __restrict__ act,
                                                     const f16* __restrict__ wdh,
                                                     const int* __restrict__ lists,
                                                     const int* __restrict__ counts,
                                                     const float* __restrict__ wslot,
                                                     float* __restrict__ out) {
    int e = blockIdx.z;
    int cnt = counts[e];
    int bm = blockIdx.x * 128;
    if (bm >= cnt) return;
    int bn = blockIdx.y * 128;
    __shared__ f16 As[4096], Bs[4096];
    __shared__ int toks[128];
    int tid = threadIdx.x, lane = tid & 63, w = tid >> 6;
    int wr = w >> 1, wc = w & 1;
    if (tid < 128) {
        int i = bm + tid;
        toks[tid] = lists[e * NTOK + ((i < cnt) ? i : (cnt - 1))];
    }
    __syncthreads();
    const f16* wdb = wdh + (size_t)e * 1024 * HPAD;
    const f16* ap[2]; const f16* bp[2];
#pragma unroll
    for (int i = 0; i < 2; i++) {
        int ms = w * 2 + i;
        int entry = toks[ms * 16 + (lane & 15)];
        ap[i] = act + (size_t)entry * HPAD + (lane >> 4) * 8;
        bp[i] = wdb + (size_t)(bn + ms * 16 + (lane & 15)) * HPAD + (lane >> 4) * 8;
    }
    f32x4 acc[4][4] = {};
    for (int k0 = 0; k0 < HPAD; k0 += 32) {
        __syncthreads();
#pragma unroll
        for (int i = 0; i < 2; i++) {
            gll16(&As[(w * 2 + i) * 512], ap[i] + k0);
            gll16(&Bs[(w * 2 + i) * 512], bp[i] + k0);
        }
        __syncthreads();
        f16x8 af[4];
#pragma unroll
        for (int m = 0; m < 4; m++) af[m] = *(const f16x8*)&As[((wr * 4 + m) * 64 + lane) * 8];
#pragma unroll
        for (int n = 0; n < 4; n++) {
            f16x8 bf = *(const f16x8*)&Bs[((wc * 4 + n) * 64 + lane) * 8];
#pragma unroll
            for (int m = 0; m < 4; m++)
                acc[m][n] = __builtin_amdgcn_mfma_f32_16x16x32_f16(af[m], bf, acc[m][n], 0, 0, 0);
        }
    }
#pragma unroll
    for (int m = 0; m < 4; m++)
#pragma unroll
        for (int r = 0; r < 4; r++) {
            int rl = (wr * 4 + m) * 16 + (lane >> 4) * 4 + r;
            if (bm + rl < cnt) {
                int entry = toks[rl];
                float wgt = wslot[entry];
                float* orow = out + (size_t)(entry >> 1) * 1024 + bn + (lane & 15);
#pragma unroll
                for (int n = 0; n < 4; n++)
                    atomicAdd(orow + (wc * 4 + n) * 16, wgt * acc[m][n][r]);
            }
        }
}

// ---------------- launch ----------------
extern "C" void kernel_launch(void* const* d_in, const int* in_sizes, int n_in,
                              void* d_out, int out_size, void* d_ws, size_t ws_size,
                              hipStream_t stream) {
    (void)in_sizes; (void)n_in; (void)out_size; (void)ws_size;
    const float* x  = (const float*)d_in[0];
    const float* wq = (const float*)d_in[1];
    const float* wk = (const float*)d_in[2];
    const float* wv = (const float*)d_in[3];
    const float* wo = (const float*)d_in[4];
    const float* wr = (const float*)d_in[5];
    const float* wg = (const float*)d_in[6];
    const float* wu = (const float*)d_in[7];
    const float* wd = (const float*)d_in[8];
    const float* g1 = (const float*)d_in[9];
    const float* g2 = (const float*)d_in[10];
    float* out = (float*)d_out;

    float* ws    = (float*)d_ws;
    float* ropeC = ws + OFF_ROPE_C;
    float* ropeS = ws + OFF_ROPE_S;
    float* qb    = ws + OFF_Q;
    float* kb    = ws + OFF_K;
    float* vb    = ws + OFF_V;
    float* xn2   = ws + OFF_XN2;
    float* wslot = ws + OFF_WSLOT;
    int*   counts = (int*)(ws + OFF_INTS);
    int*   lists  = counts + NEXP;
    f16* xn1h  = (f16*)(ws + OFF_XN1H);
    f16* attnh = xn1h;                       // alias: xn1h dead after QKV
    f16* xn2h  = (f16*)(ws + OFF_XN2H);
    f16* wqh   = (f16*)(ws + OFF_WQH);
    f16* wkh   = (f16*)(ws + OFF_WKH);
    f16* wvh   = (f16*)(ws + OFF_WVH);
    f16* woh   = (f16*)(ws + OFF_WOH);
    f16* wgh   = (f16*)(ws + OFF_WGH);
    f16* wuh   = (f16*)(ws + OFF_WUH);
    f16* wdh   = (f16*)(ws + OFF_WDH);
    f16* act   = (f16*)(ws + OFF_Q);         // alias: q,k,v dead after attention

    // 1. rope tables (+ zero expert counters)
    rope_table_kernel<<<(SEQ * 32 + 255) / 256, 256, 0, stream>>>(ropeC, ropeS, counts);
    // 2. weight transposes fp32 -> fp16 [N][K]
    transpose_f32_f16<<<dim3(16, 16, 1), 256, 0, stream>>>(wq, wqh, 1024, 1024, 1024, 1024, 0, 0);
    transpose_f32_f16<<<dim3(16, 16, 1), 256, 0, stream>>>(wk, wkh, 1024, 1024, 1024, 1024, 0, 0);
    transpose_f32_f16<<<dim3(16, 16, 1), 256, 0, stream>>>(wv, wvh, 1024, 1024, 1024, 1024, 0, 0);
    transpose_f32_f16<<<dim3(16, 16, 1), 256, 0, stream>>>(wo, woh, 1024, 1024, 1024, 1024, 0, 0);
    transpose_f32_f16<<<dim3(16, 44, 8), 256, 0, stream>>>(wg, wgh, 1024, HIDDEN, 1024, HPAD,
                                                           (long)1024 * HIDDEN, (long)HPAD * 1024);
    transpose_f32_f16<<<dim3(16, 44, 8), 256, 0, stream>>>(wu, wuh, 1024, HIDDEN, 1024, HPAD,
                                                           (long)1024 * HIDDEN, (long)HPAD * 1024);
    transpose_f32_f16<<<dim3(44, 16, 8), 256, 0, stream>>>(wd, wdh, HIDDEN, 1024, HPAD, 1024,
                                                           (long)HIDDEN * 1024, (long)1024 * HPAD);
    // 3. rmsnorm(x,g1) -> xn1h (f16)
    rmsnorm_kernel<0><<<NTOK, 256, 0, stream>>>(x, g1, nullptr, xn1h);
    // 4. QKV projections (MFMA) -> fp32 q,k,v
    gemm_qkv<<<dim3(32, 8, 3), 256, 0, stream>>>(xn1h, wqh, wkh, wvh, qb, kb, vb);
    // 5. rope
    rope_kernel<<<(NTOK * HEADS * 32 + 255) / 256, 256, 0, stream>>>(qb, kb, ropeC, ropeS);
    // 6. flash attention -> attnh (f16)
    attn_kernel<<<dim3(SEQ / 32, BATCH * HEADS), 256, 0, stream>>>(qb, kb, vb, attnh);
    // 7. out-proj + residual -> out (= h)
    gemm_wo<<<dim3(32, 8), 256, 0, stream>>>(attnh, woh, x, out);
    // 8. rmsnorm(h,g2) -> xn2 (fp32) + xn2h (f16)
    rmsnorm_kernel<1><<<NTOK, 256, 0, stream>>>(out, g2, xn2, xn2h);
    // 9. router + top-2 dispatch
    router_kernel<<<NTOK, 64, 0, stream>>>(xn2, wr, wslot, counts, lists);
    // 10. fused gate+up (MFMA) -> act (f16, aliases q/k/v)
    moe_gateup_mfma<<<dim3(32, HPAD / 128, NEXP), 256, 0, stream>>>(xn2h, wgh, wuh, lists, counts, act);
    // 11. down (MFMA) + weighted scatter-add into out
    moe_down_mfma<<<dim3(32, 8, NEXP), 256, 0, stream>>>(act, wdh, lists, counts, wslot, out);
}

// Round 4
// 2302.064 us; speedup vs baseline: 2.8623x; 1.1225x over previous
//
#include <hip/hip_runtime.h>
#include <math.h>

#define EMBED   1024
#define HEADS   16
#define NEXP    8
#define HIDDEN  2752
#define HPAD    2816          // HIDDEN padded to 128 multiple (zero-filled)
#define SEQ     2048
#define BATCH   2
#define NTOK    (BATCH*SEQ)   // 4096

typedef _Float16 f16;
typedef __attribute__((ext_vector_type(8))) _Float16 f16x8;
typedef __attribute__((ext_vector_type(4))) float    f32x4;

// ---------------- workspace layout (float-unit offsets, all 16B aligned) ----------------
#define OFF_ROPE_C 0
#define OFF_ROPE_S (OFF_ROPE_C + 65536)
#define OFF_Q      (OFF_ROPE_S + 65536)           // q,k,v region; later aliased by act (f16)
#define OFF_K      (OFF_Q   + 4194304)
#define OFF_V      (OFF_K   + 4194304)
#define OFF_XN2    (OFF_V   + 4194304)
#define OFF_WSLOT  (OFF_XN2 + 4194304)
#define OFF_INTS   (OFF_WSLOT + 8192)             // counts[8] + lists[8*4096]
#define OFF_XN1H   (OFF_INTS + 40000)             // f16 4096x1024; aliased by attnh after QKV
#define OFF_XN2H   (OFF_XN1H + 2097152)
#define OFF_WQH    (OFF_XN2H + 2097152)
#define OFF_WKH    (OFF_WQH + 524288)
#define OFF_WVH    (OFF_WKH + 524288)
#define OFF_WOH    (OFF_WVH + 524288)
#define OFF_WGH    (OFF_WOH + 524288)             // [8][2816][1024] f16
#define OFF_WUH    (OFF_WGH + 11534336)
#define OFF_WDH    (OFF_WUH + 11534336)           // [8][1024][2816] f16

// async global->LDS, 16B per lane (LDS dest = wave-uniform base + lane*16)
__device__ __forceinline__ void gll16(void* lds, const void* g) {
    __builtin_amdgcn_global_load_lds(
        (const __attribute__((address_space(1))) unsigned int*)g,
        (__attribute__((address_space(3))) unsigned int*)lds, 16, 0, 0);
}

// ---------------- RoPE tables (double precision) + zero counters ----------------
__global__ void rope_table_kernel(float* __restrict__ cosT, float* __restrict__ sinT,
                                  int* __restrict__ counts) {
    int idx = blockIdx.x * blockDim.x + threadIdx.x;
    if (blockIdx.x == 0 && threadIdx.x < NEXP) counts[threadIdx.x] = 0;
    if (idx >= SEQ * 32) return;
    int s = idx >> 5, d = idx & 31;
    double inv = pow(10000.0, -(double)(2 * d) / 64.0);
    double ang = (double)s * inv;
    cosT[idx] = (float)cos(ang);
    sinT[idx] = (float)sin(ang);
}

// ---------------- transpose + fp32->fp16: src[K][N] -> dst[NP][KP], zero-padded ----------------
__global__ __launch_bounds__(256) void transpose_f32_f16(const float* __restrict__ src,
                                                         f16* __restrict__ dst,
                                                         int K, int N, int KP, int NP,
                                                         long sstride, long dstride) {
    src += (size_t)blockIdx.z * sstride;
    dst += (size_t)blockIdx.z * dstride;
    __shared__ float t[64][65];
    int kb = blockIdx.x * 64, nb = blockIdx.y * 64;
    int tid = threadIdx.x;
    int nc = (tid & 15) * 4, kr = tid >> 4;
#pragma unroll
    for (int r = 0; r < 4; r++) {
        int k = kb + kr + r * 16;
        float4 v = {0.f, 0.f, 0.f, 0.f};
        if (k < K && nb + nc < N)
            v = *(const float4*)&src[(size_t)k * N + nb + nc];
        t[nc + 0][kr + r * 16] = v.x;
        t[nc + 1][kr + r * 16] = v.y;
        t[nc + 2][kr + r * 16] = v.z;
        t[nc + 3][kr + r * 16] = v.w;
    }
    __syncthreads();
    int kc = (tid & 7) * 8, nr = tid >> 3;
#pragma unroll
    for (int r = 0; r < 2; r++) {
        int n = nr + r * 32;
        f16x8 o;
#pragma unroll
        for (int i = 0; i < 8; i++) o[i] = (f16)t[n][kc + i];
        *(f16x8*)&dst[(size_t)(nb + n) * KP + kb + kc] = o;
    }
}

// ---------------- RMSNorm: one block per token; writes f16 (and optional f32) ----------------
template<int DUAL>
__global__ __launch_bounds__(256) void rmsnorm_kernel(const float* __restrict__ x,
                                                      const float* __restrict__ g,
                                                      float* __restrict__ o32,
                                                      f16* __restrict__ o16) {
    int t = blockIdx.x;
    int tid = threadIdx.x;
    const float4* xr = (const float4*)(x + (size_t)t * EMBED);
    float4 v = xr[tid];
    float ss = v.x*v.x + v.y*v.y + v.z*v.z + v.w*v.w;
#pragma unroll
    for (int off = 1; off < 64; off <<= 1) ss += __shfl_xor(ss, off);
    __shared__ float red[4];
    if ((tid & 63) == 0) red[tid >> 6] = ss;
    __syncthreads();
    float tot = red[0] + red[1] + red[2] + red[3];
    float rr = 1.0f / sqrtf(tot * (1.0f / EMBED) + 1e-6f);
    float4 gv = ((const float4*)g)[tid];
    float4 ov;
    ov.x = v.x * rr * gv.x; ov.y = v.y * rr * gv.y;
    ov.z = v.z * rr * gv.z; ov.w = v.w * rr * gv.w;
    if (DUAL) ((float4*)(o32 + (size_t)t * EMBED))[tid] = ov;
    typedef __attribute__((ext_vector_type(4))) _Float16 f16x4;
    f16x4 oh; oh[0] = (f16)ov.x; oh[1] = (f16)ov.y; oh[2] = (f16)ov.z; oh[3] = (f16)ov.w;
    *(f16x4*)(o16 + (size_t)t * EMBED + tid * 4) = oh;
}

// ---------------- fused QKV MFMA GEMM, 2-phase double-buffered ----------------
__global__ __launch_bounds__(256) void gemm_qkv(const f16* __restrict__ xh,
                                                const f16* __restrict__ wqh,
                                                const f16* __restrict__ wkh,
                                                const f16* __restrict__ wvh,
                                                float* __restrict__ q,
                                                float* __restrict__ k,
                                                float* __restrict__ v) {
    int sel = blockIdx.z;
    const f16* B = (sel == 0) ? wqh : (sel == 1) ? wkh : wvh;
    float* C = (sel == 0) ? q : (sel == 1) ? k : v;
    __shared__ f16 As[2][4096], Bs[2][4096];
    int tid = threadIdx.x, lane = tid & 63, w = tid >> 6;
    int wr = w >> 1, wc = w & 1;
    int bm = blockIdx.x * 128, bn = blockIdx.y * 128;
    const f16* ap[2]; const f16* bp[2];
#pragma unroll
    for (int i = 0; i < 2; i++) {
        int ms = w * 2 + i;
        ap[i] = xh + (size_t)(bm + ms * 16 + (lane & 15)) * 1024 + (lane >> 4) * 8;
        bp[i] = B  + (size_t)(bn + ms * 16 + (lane & 15)) * 1024 + (lane >> 4) * 8;
    }
    f32x4 acc[4][4] = {};
    auto stage = [&](int buf, int k0) {
#pragma unroll
        for (int i = 0; i < 2; i++) {
            gll16(&As[buf][(w * 2 + i) * 512], ap[i] + k0);
            gll16(&Bs[buf][(w * 2 + i) * 512], bp[i] + k0);
        }
    };
    auto compute = [&](int buf) {
        f16x8 af[4];
#pragma unroll
        for (int m = 0; m < 4; m++) af[m] = *(const f16x8*)&As[buf][((wr * 4 + m) * 64 + lane) * 8];
#pragma unroll
        for (int n = 0; n < 4; n++) {
            f16x8 bf = *(const f16x8*)&Bs[buf][((wc * 4 + n) * 64 + lane) * 8];
#pragma unroll
            for (int m = 0; m < 4; m++)
                acc[m][n] = __builtin_amdgcn_mfma_f32_16x16x32_f16(af[m], bf, acc[m][n], 0, 0, 0);
        }
    };
    stage(0, 0);
    __syncthreads();
    int cur = 0;
#pragma unroll 1
    for (int k0 = 32; k0 < 1024; k0 += 32) {
        stage(cur ^ 1, k0);   // next tile in flight during MFMA
        compute(cur);
        __syncthreads();      // implicit vmcnt(0)+lgkmcnt(0) drain
        cur ^= 1;
    }
    compute(cur);
#pragma unroll
    for (int m = 0; m < 4; m++)
#pragma unroll
        for (int r = 0; r < 4; r++) {
            int row = bm + (wr * 4 + m) * 16 + (lane >> 4) * 4 + r;
            float* crow = C + (size_t)row * 1024 + bn + (lane & 15);
#pragma unroll
            for (int n = 0; n < 4; n++) crow[(wc * 4 + n) * 16] = acc[m][n][r];
        }
}

// ---------------- WO MFMA GEMM + residual, 2-phase ----------------
__global__ __launch_bounds__(256) void gemm_wo(const f16* __restrict__ ah,
                                               const f16* __restrict__ wh,
                                               const float* __restrict__ R,
                                               float* __restrict__ C) {
    __shared__ f16 As[2][4096], Bs[2][4096];
    int tid = threadIdx.x, lane = tid & 63, w = tid >> 6;
    int wr = w >> 1, wc = w & 1;
    int bm = blockIdx.x * 128, bn = blockIdx.y * 128;
    const f16* ap[2]; const f16* bp[2];
#pragma unroll
    for (int i = 0; i < 2; i++) {
        int ms = w * 2 + i;
        ap[i] = ah + (size_t)(bm + ms * 16 + (lane & 15)) * 1024 + (lane >> 4) * 8;
        bp[i] = wh + (size_t)(bn + ms * 16 + (lane & 15)) * 1024 + (lane >> 4) * 8;
    }
    f32x4 acc[4][4] = {};
    auto stage = [&](int buf, int k0) {
#pragma unroll
        for (int i = 0; i < 2; i++) {
            gll16(&As[buf][(w * 2 + i) * 512], ap[i] + k0);
            gll16(&Bs[buf][(w * 2 + i) * 512], bp[i] + k0);
        }
    };
    auto compute = [&](int buf) {
        f16x8 af[4];
#pragma unroll
        for (int m = 0; m < 4; m++) af[m] = *(const f16x8*)&As[buf][((wr * 4 + m) * 64 + lane) * 8];
#pragma unroll
        for (int n = 0; n < 4; n++) {
            f16x8 bf = *(const f16x8*)&Bs[buf][((wc * 4 + n) * 64 + lane) * 8];
#pragma unroll
            for (int m = 0; m < 4; m++)
                acc[m][n] = __builtin_amdgcn_mfma_f32_16x16x32_f16(af[m], bf, acc[m][n], 0, 0, 0);
        }
    };
    stage(0, 0);
    __syncthreads();
    int cur = 0;
#pragma unroll 1
    for (int k0 = 32; k0 < 1024; k0 += 32) {
        stage(cur ^ 1, k0);
        compute(cur);
        __syncthreads();
        cur ^= 1;
    }
    compute(cur);
#pragma unroll
    for (int m = 0; m < 4; m++)
#pragma unroll
        for (int r = 0; r < 4; r++) {
            int row = bm + (wr * 4 + m) * 16 + (lane >> 4) * 4 + r;
            const float* rrow = R + (size_t)row * 1024 + bn + (lane & 15);
            float* crow = C + (size_t)row * 1024 + bn + (lane & 15);
#pragma unroll
            for (int n = 0; n < 4; n++) crow[(wc * 4 + n) * 16] = acc[m][n][r] + rrow[(wc * 4 + n) * 16];
        }
}

// ---------------- RoPE apply (q,k fp32 in [T, H*D] layout) ----------------
__global__ void rope_kernel(float* __restrict__ q, float* __restrict__ k,
                            const float* __restrict__ cosT, const float* __restrict__ sinT) {
    int idx = blockIdx.x * blockDim.x + threadIdx.x;
    if (idx >= NTOK * HEADS * 32) return;
    int d = idx & 31;
    int h = (idx >> 5) & 15;
    int t = idx >> 9;
    int s = t & (SEQ - 1);
    float c = cosT[s * 32 + d], sn = sinT[s * 32 + d];
    size_t base = (size_t)t * EMBED + h * 64;
    float q1 = q[base + d], q2 = q[base + d + 32];
    q[base + d]      = q1 * c - q2 * sn;
    q[base + d + 32] = q2 * c + q1 * sn;
    float k1 = k[base + d], k2 = k[base + d + 32];
    k[base + d]      = k1 * c - k2 * sn;
    k[base + d + 32] = k2 * c + k1 * sn;
}

// ---------------- flash attention (fp32), writes f16 output ----------------
__global__ __launch_bounds__(256) void attn_kernel(const float* __restrict__ q,
                                                   const float* __restrict__ k,
                                                   const float* __restrict__ v,
                                                   f16* __restrict__ oh) {
    __shared__ float Qs[32][68], Ks[32][68], Vs[32][68];
    __shared__ float Ss[32][36];
    int qt = blockIdx.x;
    int bh = blockIdx.y;
    int b = bh >> 4, h = bh & 15;
    int tid = threadIdx.x;
    int qi = tid >> 3, j = tid & 7;
    {
        int c = j * 8;
        size_t gq = ((size_t)(b * SEQ + qt * 32 + qi)) * EMBED + h * 64 + c;
        *(float4*)&Qs[qi][c]     = *(const float4*)&q[gq];
        *(float4*)&Qs[qi][c + 4] = *(const float4*)&q[gq + 4];
    }
    float O[8] = {};
    float m = -INFINITY, l = 0.0f;
    const float scale = 0.125f;
    int qg = qt * 32 + qi;
    for (int kt = 0; kt <= qt; ++kt) {
        __syncthreads();
        {
            int c = j * 8;
            size_t gk = ((size_t)(b * SEQ + kt * 32 + qi)) * EMBED + h * 64 + c;
            *(float4*)&Ks[qi][c]     = *(const float4*)&k[gk];
            *(float4*)&Ks[qi][c + 4] = *(const float4*)&k[gk + 4];
            *(float4*)&Vs[qi][c]     = *(const float4*)&v[gk];
            *(float4*)&Vs[qi][c + 4] = *(const float4*)&v[gk + 4];
        }
        __syncthreads();
        float sc[4];
#pragma unroll
        for (int kkk = 0; kkk < 4; kkk++) {
            int kk = j + 8 * kkk;
            float acc = 0.0f;
#pragma unroll
            for (int dd = 0; dd < 64; dd += 4) {
                float4 qv = *(const float4*)&Qs[qi][dd];
                float4 kv = *(const float4*)&Ks[kk][dd];
                acc = fmaf(qv.x, kv.x, acc); acc = fmaf(qv.y, kv.y, acc);
                acc = fmaf(qv.z, kv.z, acc); acc = fmaf(qv.w, kv.w, acc);
            }
            int kg = kt * 32 + kk;
            sc[kkk] = (kg <= qg) ? acc * scale : -INFINITY;
        }
        float tmax = fmaxf(fmaxf(sc[0], sc[1]), fmaxf(sc[2], sc[3]));
#pragma unroll
        for (int off = 1; off < 8; off <<= 1) tmax = fmaxf(tmax, __shfl_xor(tmax, off));
        float mnew = fmaxf(m, tmax);
        float p[4], ls = 0.0f;
#pragma unroll
        for (int kkk = 0; kkk < 4; kkk++) { p[kkk] = expf(sc[kkk] - mnew); ls += p[kkk]; }
#pragma unroll
        for (int off = 1; off < 8; off <<= 1) ls += __shfl_xor(ls, off);
        float sc_old = expf(m - mnew);
        l = l * sc_old + ls;
#pragma unroll
        for (int dd = 0; dd < 8; dd++) O[dd] *= sc_old;
        m = mnew;
#pragma unroll
        for (int kkk = 0; kkk < 4; kkk++) Ss[qi][j + 8 * kkk] = p[kkk];
        __syncthreads();
#pragma unroll
        for (int kk = 0; kk < 32; kk++) {
            float pv = Ss[qi][kk];
            float4 v0 = *(const float4*)&Vs[kk][j * 8];
            float4 v1 = *(const float4*)&Vs[kk][j * 8 + 4];
            O[0] = fmaf(pv, v0.x, O[0]); O[1] = fmaf(pv, v0.y, O[1]);
            O[2] = fmaf(pv, v0.z, O[2]); O[3] = fmaf(pv, v0.w, O[3]);
            O[4] = fmaf(pv, v1.x, O[4]); O[5] = fmaf(pv, v1.y, O[5]);
            O[6] = fmaf(pv, v1.z, O[6]); O[7] = fmaf(pv, v1.w, O[7]);
        }
    }
    float inv = 1.0f / l;
    size_t go = ((size_t)(b * SEQ + qt * 32 + qi)) * EMBED + h * 64 + j * 8;
    f16x8 ov;
#pragma unroll
    for (int dd = 0; dd < 8; dd++) ov[dd] = (f16)(O[dd] * inv);
    *(f16x8*)&oh[go] = ov;
}

// ---------------- router: one wave per token, top-2 dispatch (fp32) ----------------
__global__ __launch_bounds__(64) void router_kernel(const float* __restrict__ xn2,
                                                    const float* __restrict__ wr,
                                                    float* __restrict__ wslot,
                                                    int* __restrict__ counts,
                                                    int* __restrict__ lists) {
    int t = blockIdx.x;
    int lane = threadIdx.x;
    float acc[NEXP] = {};
    for (int i = lane; i < EMBED; i += 64) {
        float xv = xn2[(size_t)t * EMBED + i];
        const float* wrow = wr + (size_t)i * NEXP;
#pragma unroll
        for (int e = 0; e < NEXP; e++) acc[e] = fmaf(xv, wrow[e], acc[e]);
    }
#pragma unroll
    for (int off = 1; off < 64; off <<= 1)
#pragma unroll
        for (int e = 0; e < NEXP; e++) acc[e] += __shfl_xor(acc[e], off);
    if (lane == 0) {
        int e1 = 0; float b1 = acc[0];
#pragma unroll
        for (int e = 1; e < NEXP; e++) if (acc[e] > b1) { b1 = acc[e]; e1 = e; }
        int e2 = -1; float b2 = -INFINITY;
#pragma unroll
        for (int e = 0; e < NEXP; e++) if (e != e1 && acc[e] > b2) { b2 = acc[e]; e2 = e; }
        float p2 = expf(b2 - b1);
        float inv = 1.0f / (1.0f + p2);
        int pos1 = atomicAdd(&counts[e1], 1);
        lists[e1 * NTOK + pos1] = (t << 1) | 0;
        wslot[t * 2 + 0] = inv;
        int pos2 = atomicAdd(&counts[e2], 1);
        lists[e2 * NTOK + pos2] = (t << 1) | 1;
        wslot[t * 2 + 1] = p2 * inv;
    }
}

// ---------------- MoE gate+up fused MFMA, 2-phase double-buffered ----------------
__global__ __launch_bounds__(256) void moe_gateup_mfma(const f16* __restrict__ xh2,
                                                       const f16* __restrict__ wgh,
                                                       const f16* __restrict__ wuh,
                                                       const int* __restrict__ lists,
                                                       const int* __restrict__ counts,
                                                       f16* __restrict__ act) {
    int e = blockIdx.z;
    int cnt = counts[e];
    int bm = blockIdx.x * 128;
    if (bm >= cnt) return;
    int bn = blockIdx.y * 128;
    __shared__ f16 As[2][4096], Gs[2][4096], Us[2][4096];
    __shared__ int toks[128];
    int tid = threadIdx.x, lane = tid & 63, w = tid >> 6;
    int wr = w >> 1, wc = w & 1;
    if (tid < 128) {
        int i = bm + tid;
        toks[tid] = lists[e * NTOK + ((i < cnt) ? i : (cnt - 1))];
    }
    __syncthreads();
    const f16* wgb = wgh + (size_t)e * HPAD * 1024;
    const f16* wub = wuh + (size_t)e * HPAD * 1024;
    const f16* ap[2]; const f16* gp[2]; const f16* up[2];
#pragma unroll
    for (int i = 0; i < 2; i++) {
        int ms = w * 2 + i;
        int entry = toks[ms * 16 + (lane & 15)];
        ap[i] = xh2 + (size_t)(entry >> 1) * 1024 + (lane >> 4) * 8;
        int col = bn + ms * 16 + (lane & 15);
        gp[i] = wgb + (size_t)col * 1024 + (lane >> 4) * 8;
        up[i] = wub + (size_t)col * 1024 + (lane >> 4) * 8;
    }
    f32x4 aG[4][4] = {}, aU[4][4] = {};
    auto stage = [&](int buf, int k0) {
#pragma unroll
        for (int i = 0; i < 2; i++) {
            gll16(&As[buf][(w * 2 + i) * 512], ap[i] + k0);
            gll16(&Gs[buf][(w * 2 + i) * 512], gp[i] + k0);
            gll16(&Us[buf][(w * 2 + i) * 512], up[i] + k0);
        }
    };
    auto compute = [&](int buf) {
        f16x8 af[4];
#pragma unroll
        for (int m = 0; m < 4; m++) af[m] = *(const f16x8*)&As[buf][((wr * 4 + m) * 64 + lane) * 8];
#pragma unroll
        for (int n = 0; n < 4; n++) {
            f16x8 bg = *(const f16x8*)&Gs[buf][((wc * 4 + n) * 64 + lane) * 8];
            f16x8 bu = *(const f16x8*)&Us[buf][((wc * 4 + n) * 64 + lane) * 8];
#pragma unroll
            for (int m = 0; m < 4; m++) {
                aG[m][n] = __builtin_amdgcn_mfma_f32_16x16x32_f16(af[m], bg, aG[m][n], 0, 0, 0);
                aU[m][n] = __builtin_amdgcn_mfma_f32_16x16x32_f16(af[m], bu, aU[m][n], 0, 0, 0);
            }
        }
    };
    stage(0, 0);
    __syncthreads();
    int cur = 0;
#pragma unroll 1
    for (int k0 = 32; k0 < 1024; k0 += 32) {
        stage(cur ^ 1, k0);
        compute(cur);
        __syncthreads();
        cur ^= 1;
    }
    compute(cur);
#pragma unroll
    for (int m = 0; m < 4; m++)
#pragma unroll
        for (int r = 0; r < 4; r++) {
            int rl = (wr * 4 + m) * 16 + (lane >> 4) * 4 + r;
            if (bm + rl < cnt) {
                int entry = toks[rl];
                f16* arow = act + (size_t)entry * HPAD + bn + (lane & 15);
#pragma unroll
                for (int n = 0; n < 4; n++) {
                    float g = aG[m][n][r], u = aU[m][n][r];
                    arow[(wc * 4 + n) * 16] = (f16)(g / (1.0f + expf(-g)) * u);
                }
            }
        }
}

// ---------------- MoE down MFMA, 2-phase: out[t] += wslot * act[entry] @ wd ----------------
__global__ __launch_bounds__(256) void moe_down_mfma(const f16* __restrict__ act,
                                                     const f16* __restrict__ wdh,
                                                     const int* __restrict__ lists,
                                                     const int* __restrict__ counts,
                                                     const float* __restrict__ wslot,
                                                     float* __restrict__ out) {
    int e = blockIdx.z;
    int cnt = counts[e];
    int bm = blockIdx.x * 128;
    if (bm >= cnt) return;
    int bn = blockIdx.y * 128;
    __shared__ f16 As[2][4096], Bs[2][4096];
    __shared__ int toks[128];
    int tid = threadIdx.x, lane = tid & 63, w = tid >> 6;
    int wr = w >> 1, wc = w & 1;
    if (tid < 128) {
        int i = bm + tid;
        toks[tid] = lists[e * NTOK + ((i < cnt) ? i : (cnt - 1))];
    }
    __syncthreads();
    const f16* wdb = wdh + (size_t)e * 1024 * HPAD;
    const f16* ap[2]; const f16* bp[2];
#pragma unroll
    for (int i = 0; i < 2; i++) {
        int ms = w * 2 + i;
        int entry = toks[ms * 16 + (lane & 15)];
        ap[i] = act + (size_t)entry * HPAD + (lane >> 4) * 8;
        bp[i] = wdb + (size_t)(bn + ms * 16 + (lane & 15)) * HPAD + (lane >> 4) * 8;
    }
    f32x4 acc[4][4] = {};
    auto stage = [&](int buf, int k0) {
#pragma unroll
        for (int i = 0; i < 2; i++) {
            gll16(&As[buf][(w * 2 + i) * 512], ap[i] + k0);
            gll16(&Bs[buf][(w * 2 + i) * 512], bp[i] + k0);
        }
    };
    auto compute = [&](int buf) {
        f16x8 af[4];
#pragma unroll
        for (int m = 0; m < 4; m++) af[m] = *(const f16x8*)&As[buf][((wr * 4 + m) * 64 + lane) * 8];
#pragma unroll
        for (int n = 0; n < 4; n++) {
            f16x8 bf = *(const f16x8*)&Bs[buf][((wc * 4 + n) * 64 + lane) * 8];
#pragma unroll
            for (int m = 0; m < 4; m++)
                acc[m][n] = __builtin_amdgcn_mfma_f32_16x16x32_f16(af[m], bf, acc[m][n], 0, 0, 0);
        }
    };
    stage(0, 0);
    __syncthreads();
    int cur = 0;
#pragma unroll 1
    for (int k0 = 32; k0 < HPAD; k0 += 32) {
        stage(cur ^ 1, k0);
        compute(cur);
        __syncthreads();
        cur ^= 1;
    }
    compute(cur);
#pragma unroll
    for (int m = 0; m < 4; m++)
#pragma unroll
        for (int r = 0; r < 4; r++) {
            int rl = (wr * 4 + m) * 16 + (lane >> 4) * 4 + r;
            if (bm + rl < cnt) {
                int entry = toks[rl];
                float wgt = wslot[entry];
                float* orow = out + (size_t)(entry >> 1) * 1024 + bn + (lane & 15);
#pragma unroll
                for (int n = 0; n < 4; n++)
                    atomicAdd(orow + (wc * 4 + n) * 16, wgt * acc[m][n][r]);
            }
        }
}

// ---------------- launch ----------------
extern "C" void kernel_launch(void* const* d_in, const int* in_sizes, int n_in,
                              void* d_out, int out_size, void* d_ws, size_t ws_size,
                              hipStream_t stream) {
    (void)in_sizes; (void)n_in; (void)out_size; (void)ws_size;
    const float* x  = (const float*)d_in[0];
    const float* wq = (const float*)d_in[1];
    const float* wk = (const float*)d_in[2];
    const float* wv = (const float*)d_in[3];
    const float* wo = (const float*)d_in[4];
    const float* wr = (const float*)d_in[5];
    const float* wg = (const float*)d_in[6];
    const float* wu = (const float*)d_in[7];
    const float* wd = (const float*)d_in[8];
    const float* g1 = (const float*)d_in[9];
    const float* g2 = (const float*)d_in[10];
    float* out = (float*)d_out;

    float* ws    = (float*)d_ws;
    float* ropeC = ws + OFF_ROPE_C;
    float* ropeS = ws + OFF_ROPE_S;
    float* qb    = ws + OFF_Q;
    float* kb    = ws + OFF_K;
    float* vb    = ws + OFF_V;
    float* xn2   = ws + OFF_XN2;
    float* wslot = ws + OFF_WSLOT;
    int*   counts = (int*)(ws + OFF_INTS);
    int*   lists  = counts + NEXP;
    f16* xn1h  = (f16*)(ws + OFF_XN1H);
    f16* attnh = xn1h;                       // alias: xn1h dead after QKV
    f16* xn2h  = (f16*)(ws + OFF_XN2H);
    f16* wqh   = (f16*)(ws + OFF_WQH);
    f16* wkh   = (f16*)(ws + OFF_WKH);
    f16* wvh   = (f16*)(ws + OFF_WVH);
    f16* woh   = (f16*)(ws + OFF_WOH);
    f16* wgh   = (f16*)(ws + OFF_WGH);
    f16* wuh   = (f16*)(ws + OFF_WUH);
    f16* wdh   = (f16*)(ws + OFF_WDH);
    f16* act   = (f16*)(ws + OFF_Q);         // alias: q,k,v dead after attention

    // 1. rope tables (+ zero expert counters)
    rope_table_kernel<<<(SEQ * 32 + 255) / 256, 256, 0, stream>>>(ropeC, ropeS, counts);
    // 2. weight transposes fp32 -> fp16 [N][K]
    transpose_f32_f16<<<dim3(16, 16, 1), 256, 0, stream>>>(wq, wqh, 1024, 1024, 1024, 1024, 0, 0);
    transpose_f32_f16<<<dim3(16, 16, 1), 256, 0, stream>>>(wk, wkh, 1024, 1024, 1024, 1024, 0, 0);
    transpose_f32_f16<<<dim3(16, 16, 1), 256, 0, stream>>>(wv, wvh, 1024, 1024, 1024, 1024, 0, 0);
    transpose_f32_f16<<<dim3(16, 16, 1), 256, 0, stream>>>(wo, woh, 1024, 1024, 1024, 1024, 0, 0);
    transpose_f32_f16<<<dim3(16, 44, 8), 256, 0, stream>>>(wg, wgh, 1024, HIDDEN, 1024, HPAD,
                                                           (long)1024 * HIDDEN, (long)HPAD * 1024);
    transpose_f32_f16<<<dim3(16, 44, 8), 256, 0, stream>>>(wu, wuh, 1024, HIDDEN, 1024, HPAD,
                                                           (long)1024 * HIDDEN, (long)HPAD * 1024);
    transpose_f32_f16<<<dim3(44, 16, 8), 256, 0, stream>>>(wd, wdh, HIDDEN, 1024, HPAD, 1024,
                                                           (long)HIDDEN * 1024, (long)1024 * HPAD);
    // 3. rmsnorm(x,g1) -> xn1h (f16)
    rmsnorm_kernel<0><<<NTOK, 256, 0, stream>>>(x, g1, nullptr, xn1h);
    // 4. QKV projections (MFMA) -> fp32 q,k,v
    gemm_qkv<<<dim3(32, 8, 3), 256, 0, stream>>>(xn1h, wqh, wkh, wvh, qb, kb, vb);
    // 5. rope
    rope_kernel<<<(NTOK * HEADS * 32 + 255) / 256, 256, 0, stream>>>(qb, kb, ropeC, ropeS);
    // 6. flash attention -> attnh (f16)
    attn_kernel<<<dim3(SEQ / 32, BATCH * HEADS), 256, 0, stream>>>(qb, kb, vb, attnh);
    // 7. out-proj + residual -> out (= h)
    gemm_wo<<<dim3(32, 8), 256, 0, stream>>>(attnh, woh, x, out);
    // 8. rmsnorm(h,g2) -> xn2 (fp32) + xn2h (f16)
    rmsnorm_kernel<1><<<NTOK, 256, 0, stream>>>(out, g2, xn2, xn2h);
    // 9. router + top-2 dispatch
    router_kernel<<<NTOK, 64, 0, stream>>>(xn2, wr, wslot, counts, lists);
    // 10. fused gate+up (MFMA) -> act (f16, aliases q/k/v)
    moe_gateup_mfma<<<dim3(32, HPAD / 128, NEXP), 256, 0, stream>>>(xn2h, wgh, wuh, lists, counts, act);
    // 11. down (MFMA) + weighted scatter-add into out
    moe_down_mfma<<<dim3(32, 8, NEXP), 256, 0, stream>>>(act, wdh, lists, counts, wslot, out);
}

// Round 10
// 1497.865 us; speedup vs baseline: 4.3991x; 1.5369x over previous
//
#include <hip/hip_runtime.h>
#include <math.h>

#define EMBED   1024
#define HEADS   16
#define NEXP    8
#define HIDDEN  2752
#define HPAD    2816          // HIDDEN padded to 128 multiple (zero-filled)
#define SEQ     2048
#define BATCH   2
#define NTOK    (BATCH*SEQ)   // 4096

typedef _Float16 f16;
typedef __attribute__((ext_vector_type(8))) _Float16 f16x8;
typedef __attribute__((ext_vector_type(4))) float    f32x4;

// ---------------- workspace layout (float-unit offsets, all 16B aligned) ----------------
#define OFF_ROPE_C 0
#define OFF_ROPE_S (OFF_ROPE_C + 65536)
#define OFF_Q      (OFF_ROPE_S + 65536)           // q,k,v fp32; vth aliases Q after rope; act aliases later
#define OFF_K      (OFF_Q   + 4194304)
#define OFF_V      (OFF_K   + 4194304)
#define OFF_XN2    (OFF_V   + 4194304)            // qh/kh (f16) alias here until step 9 writes xn2
#define OFF_WSLOT  (OFF_XN2 + 4194304)
#define OFF_INTS   (OFF_WSLOT + 8192)             // counts[8] + lists[8*4096]
#define OFF_XN1H   (OFF_INTS + 40000)             // f16 4096x1024; aliased by attnh after QKV
#define OFF_XN2H   (OFF_XN1H + 2097152)
#define OFF_WQH    (OFF_XN2H + 2097152)
#define OFF_WKH    (OFF_WQH + 524288)
#define OFF_WVH    (OFF_WKH + 524288)
#define OFF_WOH    (OFF_WVH + 524288)
#define OFF_WGH    (OFF_WOH + 524288)             // [8][2816][1024] f16
#define OFF_WUH    (OFF_WGH + 11534336)
#define OFF_WDH    (OFF_WUH + 11534336)           // [8][1024][2816] f16

// bijective XCD-chunk swizzle: consecutive remapped ids stay on one XCD (nwg % 8 == 0)
__device__ __forceinline__ int xcd_swz(int flat, int nwg) {
    int per = nwg >> 3;
    return (flat & 7) * per + (flat >> 3);
}

// ---------------- RoPE tables (double precision) + zero counters ----------------
__global__ void rope_table_kernel(float* __restrict__ cosT, float* __restrict__ sinT,
                                  int* __restrict__ counts) {
    int idx = blockIdx.x * blockDim.x + threadIdx.x;
    if (blockIdx.x == 0 && threadIdx.x < NEXP) counts[threadIdx.x] = 0;
    if (idx >= SEQ * 32) return;
    int s = idx >> 5, d = idx & 31;
    double inv = pow(10000.0, -(double)(2 * d) / 64.0);
    double ang = (double)s * inv;
    cosT[idx] = (float)cos(ang);
    sinT[idx] = (float)sin(ang);
}

// ---------------- transpose + fp32->fp16: src[K][N] -> dst[NP][KP], zero-padded ----------------
__global__ __launch_bounds__(256) void transpose_f32_f16(const float* __restrict__ src,
                                                         f16* __restrict__ dst,
                                                         int K, int N, int KP, int NP,
                                                         long sstride, long dstride) {
    src += (size_t)blockIdx.z * sstride;
    dst += (size_t)blockIdx.z * dstride;
    __shared__ float t[64][65];
    int kb = blockIdx.x * 64, nb = blockIdx.y * 64;
    int tid = threadIdx.x;
    int nc = (tid & 15) * 4, kr = tid >> 4;
#pragma unroll
    for (int r = 0; r < 4; r++) {
        int k = kb + kr + r * 16;
        float4 v = {0.f, 0.f, 0.f, 0.f};
        if (k < K && nb + nc < N)
            v = *(const float4*)&src[(size_t)k * N + nb + nc];
        t[nc + 0][kr + r * 16] = v.x;
        t[nc + 1][kr + r * 16] = v.y;
        t[nc + 2][kr + r * 16] = v.z;
        t[nc + 3][kr + r * 16] = v.w;
    }
    __syncthreads();
    int kc = (tid & 7) * 8, nr = tid >> 3;
#pragma unroll
    for (int r = 0; r < 2; r++) {
        int n = nr + r * 32;
        f16x8 o;
#pragma unroll
        for (int i = 0; i < 8; i++) o[i] = (f16)t[n][kc + i];
        *(f16x8*)&dst[(size_t)(nb + n) * KP + kb + kc] = o;
    }
}

// ---------------- RMSNorm: one block per token; writes f16 (and optional f32) ----------------
template<int DUAL>
__global__ __launch_bounds__(256) void rmsnorm_kernel(const float* __restrict__ x,
                                                      const float* __restrict__ g,
                                                      float* __restrict__ o32,
                                                      f16* __restrict__ o16) {
    int t = blockIdx.x;
    int tid = threadIdx.x;
    const float4* xr = (const float4*)(x + (size_t)t * EMBED);
    float4 v = xr[tid];
    float ss = v.x*v.x + v.y*v.y + v.z*v.z + v.w*v.w;
#pragma unroll
    for (int off = 1; off < 64; off <<= 1) ss += __shfl_xor(ss, off);
    __shared__ float red[4];
    if ((tid & 63) == 0) red[tid >> 6] = ss;
    __syncthreads();
    float tot = red[0] + red[1] + red[2] + red[3];
    float rr = 1.0f / sqrtf(tot * (1.0f / EMBED) + 1e-6f);
    float4 gv = ((const float4*)g)[tid];
    float4 ov;
    ov.x = v.x * rr * gv.x; ov.y = v.y * rr * gv.y;
    ov.z = v.z * rr * gv.z; ov.w = v.w * rr * gv.w;
    if (DUAL) ((float4*)(o32 + (size_t)t * EMBED))[tid] = ov;
    typedef __attribute__((ext_vector_type(4))) _Float16 f16x4;
    f16x4 oh; oh[0] = (f16)ov.x; oh[1] = (f16)ov.y; oh[2] = (f16)ov.z; oh[3] = (f16)ov.w;
    *(f16x4*)(o16 + (size_t)t * EMBED + tid * 4) = oh;
}

// ---------------- fused QKV: barrier-free direct-to-reg MFMA GEMM ----------------
// 1D grid 768 = 32(x) * 8(y) * 3(sel); XCD-swizzled
__global__ __launch_bounds__(256) void gemm_qkv(const f16* __restrict__ xh,
                                                const f16* __restrict__ wqh,
                                                const f16* __restrict__ wkh,
                                                const f16* __restrict__ wvh,
                                                float* __restrict__ q,
                                                float* __restrict__ k,
                                                float* __restrict__ v) {
    int wgid = xcd_swz(blockIdx.x, 768);
    int sel = wgid >> 8;
    int rem = wgid & 255;
    int bm = (rem & 31) * 128, bn = (rem >> 5) * 128;
    const f16* B = (sel == 0) ? wqh : (sel == 1) ? wkh : wvh;
    float* C = (sel == 0) ? q : (sel == 1) ? k : v;
    int tid = threadIdx.x, lane = tid & 63, w = tid >> 6;
    int wr = w >> 1, wc = w & 1;
    const f16* ar[4]; const f16* br[4];
#pragma unroll
    for (int m = 0; m < 4; m++)
        ar[m] = xh + (size_t)(bm + (wr * 4 + m) * 16 + (lane & 15)) * 1024 + (lane >> 4) * 8;
#pragma unroll
    for (int n = 0; n < 4; n++)
        br[n] = B + (size_t)(bn + (wc * 4 + n) * 16 + (lane & 15)) * 1024 + (lane >> 4) * 8;
    f32x4 acc[4][4] = {};
#pragma unroll 2
    for (int k0 = 0; k0 < 1024; k0 += 32) {
        f16x8 af[4], bf[4];
#pragma unroll
        for (int m = 0; m < 4; m++) af[m] = *(const f16x8*)(ar[m] + k0);
#pragma unroll
        for (int n = 0; n < 4; n++) bf[n] = *(const f16x8*)(br[n] + k0);
#pragma unroll
        for (int n = 0; n < 4; n++)
#pragma unroll
            for (int m = 0; m < 4; m++)
                acc[m][n] = __builtin_amdgcn_mfma_f32_16x16x32_f16(af[m], bf[n], acc[m][n], 0, 0, 0);
    }
#pragma unroll
    for (int m = 0; m < 4; m++)
#pragma unroll
        for (int r = 0; r < 4; r++) {
            int row = bm + (wr * 4 + m) * 16 + (lane >> 4) * 4 + r;
            float* crow = C + (size_t)row * 1024 + bn + (lane & 15);
#pragma unroll
            for (int n = 0; n < 4; n++) crow[(wc * 4 + n) * 16] = acc[m][n][r];
        }
}

// ---------------- WO GEMM + residual, barrier-free ----------------
__global__ __launch_bounds__(256) void gemm_wo(const f16* __restrict__ ah,
                                               const f16* __restrict__ wh,
                                               const float* __restrict__ R,
                                               float* __restrict__ C) {
    int wgid = xcd_swz(blockIdx.x, 256);
    int bm = (wgid & 31) * 128, bn = (wgid >> 5) * 128;
    int tid = threadIdx.x, lane = tid & 63, w = tid >> 6;
    int wr = w >> 1, wc = w & 1;
    const f16* ar[4]; const f16* br[4];
#pragma unroll
    for (int m = 0; m < 4; m++)
        ar[m] = ah + (size_t)(bm + (wr * 4 + m) * 16 + (lane & 15)) * 1024 + (lane >> 4) * 8;
#pragma unroll
    for (int n = 0; n < 4; n++)
        br[n] = wh + (size_t)(bn + (wc * 4 + n) * 16 + (lane & 15)) * 1024 + (lane >> 4) * 8;
    f32x4 acc[4][4] = {};
#pragma unroll 2
    for (int k0 = 0; k0 < 1024; k0 += 32) {
        f16x8 af[4], bf[4];
#pragma unroll
        for (int m = 0; m < 4; m++) af[m] = *(const f16x8*)(ar[m] + k0);
#pragma unroll
        for (int n = 0; n < 4; n++) bf[n] = *(const f16x8*)(br[n] + k0);
#pragma unroll
        for (int n = 0; n < 4; n++)
#pragma unroll
            for (int m = 0; m < 4; m++)
                acc[m][n] = __builtin_amdgcn_mfma_f32_16x16x32_f16(af[m], bf[n], acc[m][n], 0, 0, 0);
    }
#pragma unroll
    for (int m = 0; m < 4; m++)
#pragma unroll
        for (int r = 0; r < 4; r++) {
            int row = bm + (wr * 4 + m) * 16 + (lane >> 4) * 4 + r;
            const float* rrow = R + (size_t)row * 1024 + bn + (lane & 15);
            float* crow = C + (size_t)row * 1024 + bn + (lane & 15);
#pragma unroll
            for (int n = 0; n < 4; n++) crow[(wc * 4 + n) * 16] = acc[m][n][r] + rrow[(wc * 4 + n) * 16];
        }
}

// ---------------- RoPE apply: fp32 q,k -> f16 qh,kh ----------------
__global__ void rope_kernel(const float* __restrict__ q, const float* __restrict__ k,
                            f16* __restrict__ qh, f16* __restrict__ kh,
                            const float* __restrict__ cosT, const float* __restrict__ sinT) {
    int idx = blockIdx.x * blockDim.x + threadIdx.x;
    if (idx >= NTOK * HEADS * 32) return;
    int d = idx & 31;
    int h = (idx >> 5) & 15;
    int t = idx >> 9;
    int s = t & (SEQ - 1);
    float c = cosT[s * 32 + d], sn = sinT[s * 32 + d];
    size_t base = (size_t)t * EMBED + h * 64;
    float q1 = q[base + d], q2 = q[base + d + 32];
    qh[base + d]      = (f16)(q1 * c - q2 * sn);
    qh[base + d + 32] = (f16)(q2 * c + q1 * sn);
    float k1 = k[base + d], k2 = k[base + d + 32];
    kh[base + d]      = (f16)(k1 * c - k2 * sn);
    kh[base + d + 32] = (f16)(k2 * c + k1 * sn);
}

// ---------------- V transpose: fp32 v[tok][1024] -> f16 vth[b][h][64 d][2048 s] ----------------
__global__ __launch_bounds__(256) void vt_kernel(const float* __restrict__ v,
                                                 f16* __restrict__ vth) {
    int bh = blockIdx.y, b = bh >> 4, h = bh & 15;
    int s0 = blockIdx.x * 64;
    __shared__ float t[64][65];   // t[d][s]
    int tid = threadIdx.x;
    int sl = tid >> 4, dc = (tid & 15) * 4;
#pragma unroll
    for (int r = 0; r < 4; r++) {
        int s = sl + r * 16;
        float4 vv = *(const float4*)&v[(size_t)(b * SEQ + s0 + s) * 1024 + h * 64 + dc];
        t[dc + 0][s] = vv.x; t[dc + 1][s] = vv.y;
        t[dc + 2][s] = vv.z; t[dc + 3][s] = vv.w;
    }
    __syncthreads();
    int dl = tid >> 3, sc = (tid & 7) * 8;
#pragma unroll
    for (int r = 0; r < 2; r++) {
        int d = dl + r * 32;
        f16x8 o;
#pragma unroll
        for (int i = 0; i < 8; i++) o[i] = (f16)t[d][sc + i];
        *(f16x8*)&vth[((size_t)(b * 16 + h) * 64 + d) * 2048 + s0 + sc] = o;
    }
}

// ---------------- MFMA flash attention: barrier-free, 4 waves x 16 q-rows ----------------
// grid 1024 = 32 bh * 32 qt; XCD-swizzled so same (b,h) K/V stays L2-resident
__global__ __launch_bounds__(256) void attn_mfma(const f16* __restrict__ qh,
                                                 const f16* __restrict__ kh,
                                                 const f16* __restrict__ vth,
                                                 f16* __restrict__ oh) {
    int wgid = xcd_swz(blockIdx.x, 1024);
    int bh = wgid >> 5, qt = wgid & 31;
    int b = bh >> 4, h = bh & 15;
    int tid = threadIdx.x, lane = tid & 63, w = tid >> 6;
    __shared__ __align__(16) f16 plds[4][16][40];   // per-wave P tile, padded rows (80B)
    int lr = lane & 15, lc = lane >> 4;
    int wq0 = qt * 64 + w * 16;                     // sequence-local first q row of this wave
    // Q fragments in registers: A[row=lr][d-chunk lc*8], two d-chunks (0..31, 32..63)
    const f16* qbase = qh + (size_t)(b * SEQ + wq0 + lr) * 1024 + h * 64 + lc * 8;
    f16x8 qa0 = *(const f16x8*)qbase;
    f16x8 qa1 = *(const f16x8*)(qbase + 32);
    f32x4 O[4] = {};                                 // O[dn]: col=dn*16+lr, row=lc*4+r
    float mrow[4], lrow[4];
#pragma unroll
    for (int r = 0; r < 4; r++) { mrow[r] = -INFINITY; lrow[r] = 0.f; }
    const f16* kbase = kh + (size_t)(b * SEQ + lr) * 1024 + h * 64 + lc * 8;
    const f16* vbase = vth + ((size_t)(b * 16 + h) * 64 + lr) * 2048 + lc * 8;
    int qmax = wq0 + 15;
#pragma unroll 1
    for (int kv0 = 0; kv0 <= qmax; kv0 += 32) {
        // QK^T: S[q][k], q=lc*4+r (+wq0), k=n*16+lr (+kv0)
        f32x4 s0v = {}, s1v = {};
        {
            const f16* kp0 = kbase + (size_t)kv0 * 1024;
            const f16* kp1 = kbase + (size_t)(kv0 + 16) * 1024;
            f16x8 ka0 = *(const f16x8*)kp0;
            f16x8 ka1 = *(const f16x8*)(kp0 + 32);
            f16x8 kb0 = *(const f16x8*)kp1;
            f16x8 kb1 = *(const f16x8*)(kp1 + 32);
            s0v = __builtin_amdgcn_mfma_f32_16x16x32_f16(qa0, ka0, s0v, 0, 0, 0);
            s0v = __builtin_amdgcn_mfma_f32_16x16x32_f16(qa1, ka1, s0v, 0, 0, 0);
            s1v = __builtin_amdgcn_mfma_f32_16x16x32_f16(qa0, kb0, s1v, 0, 0, 0);
            s1v = __builtin_amdgcn_mfma_f32_16x16x32_f16(qa1, kb1, s1v, 0, 0, 0);
        }
        bool tail = (kv0 + 31 > wq0);
#pragma unroll
        for (int r = 0; r < 4; r++) {
            float a = s0v[r] * 0.125f;
            float c = s1v[r] * 0.125f;
            if (tail) {
                int qg = wq0 + lc * 4 + r;
                if (kv0 + lr > qg)      a = -INFINITY;
                if (kv0 + 16 + lr > qg) c = -INFINITY;
            }
            s0v[r] = a; s1v[r] = c;
        }
        // online softmax (fp32)
        float mt[4], lt[4], sco[4];
#pragma unroll
        for (int r = 0; r < 4; r++) mt[r] = fmaxf(s0v[r], s1v[r]);
#pragma unroll
        for (int off = 1; off < 16; off <<= 1)
#pragma unroll
            for (int r = 0; r < 4; r++) mt[r] = fmaxf(mt[r], __shfl_xor(mt[r], off));
#pragma unroll
        for (int r = 0; r < 4; r++) {
            float mn = fmaxf(mrow[r], mt[r]);
            sco[r] = expf(mrow[r] - mn);
            mrow[r] = mn;
            s0v[r] = expf(s0v[r] - mn);
            s1v[r] = expf(s1v[r] - mn);
            lt[r] = s0v[r] + s1v[r];
        }
#pragma unroll
        for (int off = 1; off < 16; off <<= 1)
#pragma unroll
            for (int r = 0; r < 4; r++) lt[r] += __shfl_xor(lt[r], off);
#pragma unroll
        for (int r = 0; r < 4; r++) lrow[r] = lrow[r] * sco[r] + lt[r];
#pragma unroll
        for (int dn = 0; dn < 4; dn++)
#pragma unroll
            for (int r = 0; r < 4; r++) O[dn][r] *= sco[r];
        // P -> LDS (re-orient to A-fragment layout); same-wave DS ops are in-order,
        // and per-thread write/read index sets can alias -> compiler preserves order
#pragma unroll
        for (int r = 0; r < 4; r++) {
            plds[w][lc * 4 + r][lr]      = (f16)s0v[r];
            plds[w][lc * 4 + r][16 + lr] = (f16)s1v[r];
        }
        f16x8 pa = *(const f16x8*)&plds[w][lr][lc * 8];
        // PV: O[dn] += P[16q x 32k] * V^T[d=dn*16+lr][k]
#pragma unroll
        for (int dn = 0; dn < 4; dn++) {
            f16x8 vb = *(const f16x8*)(vbase + (size_t)(dn * 16) * 2048 + kv0);
            O[dn] = __builtin_amdgcn_mfma_f32_16x16x32_f16(pa, vb, O[dn], 0, 0, 0);
        }
    }
#pragma unroll
    for (int r = 0; r < 4; r++) {
        float inv = 1.0f / lrow[r];
        size_t row = (size_t)(b * SEQ + wq0 + lc * 4 + r) * 1024 + h * 64 + lr;
#pragma unroll
        for (int dn = 0; dn < 4; dn++)
            oh[row + dn * 16] = (f16)(O[dn][r] * inv);
    }
}

// ---------------- router: one wave per token, top-2 dispatch (fp32) ----------------
__global__ __launch_bounds__(64) void router_kernel(const float* __restrict__ xn2,
                                                    const float* __restrict__ wr,
                                                    float* __restrict__ wslot,
                                                    int* __restrict__ counts,
                                                    int* __restrict__ lists) {
    int t = blockIdx.x;
    int lane = threadIdx.x;
    float acc[NEXP] = {};
    for (int i = lane; i < EMBED; i += 64) {
        float xv = xn2[(size_t)t * EMBED + i];
        const float* wrow = wr + (size_t)i * NEXP;
#pragma unroll
        for (int e = 0; e < NEXP; e++) acc[e] = fmaf(xv, wrow[e], acc[e]);
    }
#pragma unroll
    for (int off = 1; off < 64; off <<= 1)
#pragma unroll
        for (int e = 0; e < NEXP; e++) acc[e] += __shfl_xor(acc[e], off);
    if (lane == 0) {
        int e1 = 0; float b1 = acc[0];
#pragma unroll
        for (int e = 1; e < NEXP; e++) if (acc[e] > b1) { b1 = acc[e]; e1 = e; }
        int e2 = -1; float b2 = -INFINITY;
#pragma unroll
        for (int e = 0; e < NEXP; e++) if (e != e1 && acc[e] > b2) { b2 = acc[e]; e2 = e; }
        float p2 = expf(b2 - b1);
        float inv = 1.0f / (1.0f + p2);
        int pos1 = atomicAdd(&counts[e1], 1);
        lists[e1 * NTOK + pos1] = (t << 1) | 0;
        wslot[t * 2 + 0] = inv;
        int pos2 = atomicAdd(&counts[e2], 1);
        lists[e2 * NTOK + pos2] = (t << 1) | 1;
        wslot[t * 2 + 1] = p2 * inv;
    }
}

// ---------------- MoE gate+up, barrier-free direct-to-reg: block 128x64 ----------------
__global__ __launch_bounds__(256) void moe_gateup_mfma(const f16* __restrict__ xh2,
                                                       const f16* __restrict__ wgh,
                                                       const f16* __restrict__ wuh,
                                                       const int* __restrict__ lists,
                                                       const int* __restrict__ counts,
                                                       f16* __restrict__ act) {
    int wgid = xcd_swz(blockIdx.x, 32 * 44 * NEXP);
    int e = wgid / (32 * 44);
    int rem = wgid % (32 * 44);
    int bx = rem & 31, by = rem >> 5;
    int cnt = counts[e];
    int bm = bx * 128;
    if (bm >= cnt) return;
    int bn = by * 64;
    __shared__ int toks[128];
    int tid = threadIdx.x, lane = tid & 63, w = tid >> 6;
    int wr = w >> 1, wc = w & 1;
    if (tid < 128) {
        int i = bm + tid;
        toks[tid] = lists[e * NTOK + ((i < cnt) ? i : (cnt - 1))];
    }
    __syncthreads();
    const f16* wgb = wgh + (size_t)e * HPAD * 1024;
    const f16* wub = wuh + (size_t)e * HPAD * 1024;
    const f16* ar[4]; const f16* gr[2]; const f16* ur[2];
#pragma unroll
    for (int m = 0; m < 4; m++) {
        int entry = toks[(wr * 4 + m) * 16 + (lane & 15)];
        ar[m] = xh2 + (size_t)(entry >> 1) * 1024 + (lane >> 4) * 8;
    }
#pragma unroll
    for (int n = 0; n < 2; n++) {
        int col = bn + (wc * 2 + n) * 16 + (lane & 15);
        gr[n] = wgb + (size_t)col * 1024 + (lane >> 4) * 8;
        ur[n] = wub + (size_t)col * 1024 + (lane >> 4) * 8;
    }
    f32x4 aG[4][2] = {}, aU[4][2] = {};
#pragma unroll 2
    for (int k0 = 0; k0 < 1024; k0 += 32) {
        f16x8 af[4], bg[2], bu[2];
#pragma unroll
        for (int m = 0; m < 4; m++) af[m] = *(const f16x8*)(ar[m] + k0);
#pragma unroll
        for (int n = 0; n < 2; n++) { bg[n] = *(const f16x8*)(gr[n] + k0); bu[n] = *(const f16x8*)(ur[n] + k0); }
#pragma unroll
        for (int n = 0; n < 2; n++)
#pragma unroll
            for (int m = 0; m < 4; m++) {
                aG[m][n] = __builtin_amdgcn_mfma_f32_16x16x32_f16(af[m], bg[n], aG[m][n], 0, 0, 0);
                aU[m][n] = __builtin_amdgcn_mfma_f32_16x16x32_f16(af[m], bu[n], aU[m][n], 0, 0, 0);
            }
    }
#pragma unroll
    for (int m = 0; m < 4; m++)
#pragma unroll
        for (int r = 0; r < 4; r++) {
            int rl = (wr * 4 + m) * 16 + (lane >> 4) * 4 + r;
            if (bm + rl < cnt) {
                int entry = toks[rl];
                f16* arow = act + (size_t)entry * HPAD + bn + (lane & 15);
#pragma unroll
                for (int n = 0; n < 2; n++) {
                    float g = aG[m][n][r], u = aU[m][n][r];
                    arow[(wc * 2 + n) * 16] = (f16)(g / (1.0f + expf(-g)) * u);
                }
            }
        }
}

// ---------------- MoE down, barrier-free direct-to-reg: block 128x128 ----------------
__global__ __launch_bounds__(256) void moe_down_mfma(const f16* __restrict__ act,
                                                     const f16* __restrict__ wdh,
                                                     const int* __restrict__ lists,
                                                     const int* __restrict__ counts,
                                                     const float* __restrict__ wslot,
                                                     float* __restrict__ out) {
    int wgid = xcd_swz(blockIdx.x, 32 * 8 * NEXP);
    int e = wgid >> 8;
    int rem = wgid & 255;
    int bx = rem & 31, by = rem >> 5;
    int cnt = counts[e];
    int bm = bx * 128;
    if (bm >= cnt) return;
    int bn = by * 128;
    __shared__ int toks[128];
    int tid = threadIdx.x, lane = tid & 63, w = tid >> 6;
    int wr = w >> 1, wc = w & 1;
    if (tid < 128) {
        int i = bm + tid;
        toks[tid] = lists[e * NTOK + ((i < cnt) ? i : (cnt - 1))];
    }
    __syncthreads();
    const f16* wdb = wdh + (size_t)e * 1024 * HPAD;
    const f16* ar[4]; const f16* br[4];
#pragma unroll
    for (int m = 0; m < 4; m++) {
        int entry = toks[(wr * 4 + m) * 16 + (lane & 15)];
        ar[m] = act + (size_t)entry * HPAD + (lane >> 4) * 8;
    }
#pragma unroll
    for (int n = 0; n < 4; n++)
        br[n] = wdb + (size_t)(bn + (wc * 4 + n) * 16 + (lane & 15)) * HPAD + (lane >> 4) * 8;
    f32x4 acc[4][4] = {};
#pragma unroll 2
    for (int k0 = 0; k0 < HPAD; k0 += 32) {
        f16x8 af[4], bf[4];
#pragma unroll
        for (int m = 0; m < 4; m++) af[m] = *(const f16x8*)(ar[m] + k0);
#pragma unroll
        for (int n = 0; n < 4; n++) bf[n] = *(const f16x8*)(br[n] + k0);
#pragma unroll
        for (int n = 0; n < 4; n++)
#pragma unroll
            for (int m = 0; m < 4; m++)
                acc[m][n] = __builtin_amdgcn_mfma_f32_16x16x32_f16(af[m], bf[n], acc[m][n], 0, 0, 0);
    }
#pragma unroll
    for (int m = 0; m < 4; m++)
#pragma unroll
        for (int r = 0; r < 4; r++) {
            int rl = (wr * 4 + m) * 16 + (lane >> 4) * 4 + r;
            if (bm + rl < cnt) {
                int entry = toks[rl];
                float wgt = wslot[entry];
                float* orow = out + (size_t)(entry >> 1) * 1024 + bn + (lane & 15);
#pragma unroll
                for (int n = 0; n < 4; n++)
                    atomicAdd(orow + (wc * 4 + n) * 16, wgt * acc[m][n][r]);
            }
        }
}

// ---------------- launch ----------------
extern "C" void kernel_launch(void* const* d_in, const int* in_sizes, int n_in,
                              void* d_out, int out_size, void* d_ws, size_t ws_size,
                              hipStream_t stream) {
    (void)in_sizes; (void)n_in; (void)out_size; (void)ws_size;
    const float* x  = (const float*)d_in[0];
    const float* wq = (const float*)d_in[1];
    const float* wk = (const float*)d_in[2];
    const float* wv = (const float*)d_in[3];
    const float* wo = (const float*)d_in[4];
    const float* wr = (const float*)d_in[5];
    const float* wg = (const float*)d_in[6];
    const float* wu = (const float*)d_in[7];
    const float* wd = (const float*)d_in[8];
    const float* g1 = (const float*)d_in[9];
    const float* g2 = (const float*)d_in[10];
    float* out = (float*)d_out;

    float* ws    = (float*)d_ws;
    float* ropeC = ws + OFF_ROPE_C;
    float* ropeS = ws + OFF_ROPE_S;
    float* qb    = ws + OFF_Q;
    float* kb    = ws + OFF_K;
    float* vb    = ws + OFF_V;
    float* xn2   = ws + OFF_XN2;
    float* wslot = ws + OFF_WSLOT;
    int*   counts = (int*)(ws + OFF_INTS);
    int*   lists  = counts + NEXP;
    f16* xn1h  = (f16*)(ws + OFF_XN1H);
    f16* attnh = xn1h;                       // alias: xn1h dead after QKV
    f16* xn2h  = (f16*)(ws + OFF_XN2H);
    f16* wqh   = (f16*)(ws + OFF_WQH);
    f16* wkh   = (f16*)(ws + OFF_WKH);
    f16* wvh   = (f16*)(ws + OFF_WVH);
    f16* woh   = (f16*)(ws + OFF_WOH);
    f16* wgh   = (f16*)(ws + OFF_WGH);
    f16* wuh   = (f16*)(ws + OFF_WUH);
    f16* wdh   = (f16*)(ws + OFF_WDH);
    f16* act   = (f16*)(ws + OFF_Q);         // alias: q,k,v dead after attention
    f16* qh    = (f16*)(ws + OFF_XN2);       // alias: xn2 fp32 written only at step 9
    f16* kh    = qh + (size_t)NTOK * EMBED;
    f16* vth   = (f16*)(ws + OFF_Q);         // alias: q fp32 dead after rope

    // 1. rope tables (+ zero expert counters)
    rope_table_kernel<<<(SEQ * 32 + 255) / 256, 256, 0, stream>>>(ropeC, ropeS, counts);
    // 2. weight transposes fp32 -> fp16 [N][K]
    transpose_f32_f16<<<dim3(16, 16, 1), 256, 0, stream>>>(wq, wqh, 1024, 1024, 1024, 1024, 0, 0);
    transpose_f32_f16<<<dim3(16, 16, 1), 256, 0, stream>>>(wk, wkh, 1024, 1024, 1024, 1024, 0, 0);
    transpose_f32_f16<<<dim3(16, 16, 1), 256, 0, stream>>>(wv, wvh, 1024, 1024, 1024, 1024, 0, 0);
    transpose_f32_f16<<<dim3(16, 16, 1), 256, 0, stream>>>(wo, woh, 1024, 1024, 1024, 1024, 0, 0);
    transpose_f32_f16<<<dim3(16, 44, 8), 256, 0, stream>>>(wg, wgh, 1024, HIDDEN, 1024, HPAD,
                                                           (long)1024 * HIDDEN, (long)HPAD * 1024);
    transpose_f32_f16<<<dim3(16, 44, 8), 256, 0, stream>>>(wu, wuh, 1024, HIDDEN, 1024, HPAD,
                                                           (long)1024 * HIDDEN, (long)HPAD * 1024);
    transpose_f32_f16<<<dim3(44, 16, 8), 256, 0, stream>>>(wd, wdh, HIDDEN, 1024, HPAD, 1024,
                                                           (long)HIDDEN * 1024, (long)1024 * HPAD);
    // 3. rmsnorm(x,g1) -> xn1h (f16)
    rmsnorm_kernel<0><<<NTOK, 256, 0, stream>>>(x, g1, nullptr, xn1h);
    // 4. QKV projections (MFMA, barrier-free) -> fp32 q,k,v
    gemm_qkv<<<768, 256, 0, stream>>>(xn1h, wqh, wkh, wvh, qb, kb, vb);
    // 5. rope: fp32 q,k -> f16 qh,kh
    rope_kernel<<<(NTOK * HEADS * 32 + 255) / 256, 256, 0, stream>>>(qb, kb, qh, kh, ropeC, ropeS);
    // 6. V transpose: fp32 v -> f16 vth (overwrites dead q fp32)
    vt_kernel<<<dim3(32, 32), 256, 0, stream>>>(vb, vth);
    // 7. MFMA flash attention -> attnh (f16)
    attn_mfma<<<1024, 256, 0, stream>>>(qh, kh, vth, attnh);
    // 8. out-proj + residual -> out (= h)
    gemm_wo<<<256, 256, 0, stream>>>(attnh, woh, x, out);
    // 9. rmsnorm(h,g2) -> xn2 (fp32, overwrites dead qh/kh) + xn2h (f16)
    rmsnorm_kernel<1><<<NTOK, 256, 0, stream>>>(out, g2, xn2, xn2h);
    // 10. router + top-2 dispatch
    router_kernel<<<NTOK, 64, 0, stream>>>(xn2, wr, wslot, counts, lists);
    // 11. fused gate+up (barrier-free) -> act (f16, aliases q/k/v)
    moe_gateup_mfma<<<32 * 44 * NEXP, 256, 0, stream>>>(xn2h, wgh, wuh, lists, counts, act);
    // 12. down (barrier-free) + weighted scatter-add into out
    moe_down_mfma<<<32 * 8 * NEXP, 256, 0, stream>>>(act, wdh, lists, counts, wslot, out);
}